// Round 1
// baseline (405.556 us; speedup 1.0000x reference)
//
#include <hip/hip_runtime.h>

// Problem: MultiHeadSelfAttention  B=8, N=1024, D=1024, H=16, DK=64
// x:(8,1024,1024) f32, w_qkv:(1024,3072) f32, b_qkv:(3072,), w_proj:(1024,1024), b_proj:(1024,)
// out:(8,1024,1024) f32

#define BB 8
#define NN 1024
#define DD 1024
#define HH 16
#define DK 64
#define TOK (BB * NN)        // 8192 tokens
#define QKVN (3 * DD)        // 3072

typedef __attribute__((ext_vector_type(8))) short bf16x8;
typedef __attribute__((ext_vector_type(4))) float f32x4;
typedef __attribute__((ext_vector_type(4))) short short4v;
typedef __attribute__((ext_vector_type(4))) float float4v;

static __device__ __forceinline__ short f2bf(float f) {
  union { float f; unsigned u; } v; v.f = f;
  unsigned r = (v.u + 0x7FFFu + ((v.u >> 16) & 1u)) >> 16;
  return (short)r;
}

// async global->LDS, 16B per lane. LDS dest = wave-uniform base + lane*16B.
static __device__ __forceinline__ void gload_lds16(const short* g, short* lds, int lane) {
#if __has_builtin(__builtin_amdgcn_global_load_lds)
  __builtin_amdgcn_global_load_lds((const __attribute__((address_space(1))) void*)g,
                                   (__attribute__((address_space(3))) void*)lds, 16, 0, 0);
#else
  ((bf16x8*)lds)[lane] = *(const bf16x8*)g;
#endif
}

// ---------------- cast x (f32 -> bf16), 4 elems/thread ----------------
__global__ __launch_bounds__(256) void cast_f32_bf16(const float* __restrict__ in,
                                                     short* __restrict__ out, long n) {
  long i = ((long)blockIdx.x * blockDim.x + threadIdx.x) * 4;
  if (i >= n) return;
  float4v v = *(const float4v*)(in + i);
  short4v o;
  o[0] = f2bf(v[0]); o[1] = f2bf(v[1]); o[2] = f2bf(v[2]); o[3] = f2bf(v[3]);
  *(short4v*)(out + i) = o;
}

// ------------- transpose-cast: in[rows][cols] f32 -> out[cols][rows] bf16 -------------
__global__ __launch_bounds__(256) void transpose_cast(const float* __restrict__ in,
                                                      short* __restrict__ out,
                                                      int rows, int cols) {
  __shared__ float tile[32][33];
  int bx = blockIdx.x * 32;  // col base
  int by = blockIdx.y * 32;  // row base
  int tx = threadIdx.x, ty = threadIdx.y;  // 32 x 8
#pragma unroll
  for (int q = 0; q < 4; q++)
    tile[ty + 8 * q][tx] = in[(long)(by + ty + 8 * q) * cols + bx + tx];
  __syncthreads();
#pragma unroll
  for (int q = 0; q < 4; q++)
    out[(long)(bx + ty + 8 * q) * rows + by + tx] = f2bf(tile[tx][ty + 8 * q]);
}

// ---------------- GEMM: C[M][N] = A[M][K] * Bt[N][K]^T + bias ----------------
// 128x128 tile, BK=32, 4 waves in 2x2 (64x64 each), 16x16x32 bf16 MFMA (m97 structure)
template <bool OUT_BF16>
__global__ __launch_bounds__(256) void gemm_bt(const short* __restrict__ A,
                                               const short* __restrict__ Bt,
                                               const float* __restrict__ bias,
                                               void* __restrict__ Cout,
                                               int M, int N, int K) {
  __shared__ __align__(16) short As[128 * 32];
  __shared__ __align__(16) short Bs[128 * 32];
  const int tid = threadIdx.x;
  const int w = tid >> 6, lane = tid & 63;
  const int r = lane & 15, g = lane >> 4;
  const int wm = w >> 1, wn = w & 1;
  const long tileM = (long)blockIdx.y * 128;
  const long tileN = (long)blockIdx.x * 128;

  f32x4 acc[4][4] = {};

  const int rowInChunk = lane >> 2;       // 0..15
  const int colOff = (lane & 3) * 8;      // 0,8,16,24

  for (int k0 = 0; k0 < K; k0 += 32) {
    __syncthreads();  // previous compute done before overwriting LDS
#pragma unroll
    for (int issue = 0; issue < 2; ++issue) {
      int c = w * 2 + issue;  // chunk 0..7 = rows c*16..c*16+15
      const short* ga = A + (tileM + c * 16 + rowInChunk) * (long)K + k0 + colOff;
      gload_lds16(ga, &As[c * 512], lane);
      const short* gb = Bt + (tileN + c * 16 + rowInChunk) * (long)K + k0 + colOff;
      gload_lds16(gb, &Bs[c * 512], lane);
    }
    __syncthreads();  // staging complete (compiler drains vmcnt before barrier)

    bf16x8 a[4], b[4];
#pragma unroll
    for (int i = 0; i < 4; i++)
      a[i] = *(const bf16x8*)&As[(wm * 64 + i * 16 + r) * 32 + 8 * g];
#pragma unroll
    for (int i = 0; i < 4; i++)
      b[i] = *(const bf16x8*)&Bs[(wn * 64 + i * 16 + r) * 32 + 8 * g];
#pragma unroll
    for (int i = 0; i < 4; i++)
#pragma unroll
      for (int ii = 0; ii < 4; ii++)
        acc[i][ii] = __builtin_amdgcn_mfma_f32_16x16x32_bf16(a[i], b[ii], acc[i][ii], 0, 0, 0);
  }

  // epilogue: D layout col=lane&15, row=(lane>>4)*4+reg  [guide-verified]
#pragma unroll
  for (int i = 0; i < 4; i++) {
    long rowb = tileM + wm * 64 + i * 16 + g * 4;
#pragma unroll
    for (int ii = 0; ii < 4; ii++) {
      long cn = tileN + wn * 64 + ii * 16 + r;
      float bv = bias[cn];
#pragma unroll
      for (int j = 0; j < 4; j++) {
        float v = acc[i][ii][j] + bv;
        if constexpr (OUT_BF16)
          ((short*)Cout)[(rowb + j) * N + cn] = f2bf(v);
        else
          ((float*)Cout)[(rowb + j) * N + cn] = v;
      }
    }
  }
}

// ---------------- flash attention, 1 wave / block, 16 q-rows ----------------
// qkv[(b*N+n)][3072]: Q cols h*64.., K cols 1024+h*64.., V cols 2048+h*64..
// Swapped QK^T: S^T = K * Q^T -> lane owns scores for q-row (lane&15).
// PV as O^T = V^T * P^T -> rescale + output lane-local in q.
__global__ __launch_bounds__(64) void attn_kernel(const short* __restrict__ qkv,
                                                  short* __restrict__ attn_out) {
  const int bh = blockIdx.y;
  const int bb = bh >> 4, h = bh & 15;
  const int qbase = blockIdx.x * 16;
  const int lane = threadIdx.x;
  const int r = lane & 15, g = lane >> 4;
  const int RS = QKVN;  // 3072
  const long base = (long)bb * NN * RS;
  const short* Qp = qkv + base + h * 64;
  const short* Kp = qkv + base + DD + h * 64;
  const short* Vp = qkv + base + 2 * DD + h * 64;

  // Q fragments: q-row = qbase + r, dk = 32*s + 8g..8g+7
  bf16x8 qf0 = *(const bf16x8*)(Qp + (long)(qbase + r) * RS + 8 * g);
  bf16x8 qf1 = *(const bf16x8*)(Qp + (long)(qbase + r) * RS + 32 + 8 * g);

  float m = -1e30f, lsum = 0.0f;
  f32x4 o[4] = {};  // o[t][j]: d = 16t + 4g + j, q = r

  for (int kv0 = 0; kv0 < NN; kv0 += 32) {
    const short* K0 = Kp + (long)(kv0 + r) * RS;
    const short* K1 = K0 + 16 * (long)RS;
    bf16x8 k00 = *(const bf16x8*)(K0 + 8 * g);
    bf16x8 k01 = *(const bf16x8*)(K0 + 32 + 8 * g);
    bf16x8 k10 = *(const bf16x8*)(K1 + 8 * g);
    bf16x8 k11 = *(const bf16x8*)(K1 + 32 + 8 * g);

    f32x4 s0 = {}, s1 = {};
    s0 = __builtin_amdgcn_mfma_f32_16x16x32_bf16(k00, qf0, s0, 0, 0, 0);
    s0 = __builtin_amdgcn_mfma_f32_16x16x32_bf16(k01, qf1, s0, 0, 0, 0);
    s1 = __builtin_amdgcn_mfma_f32_16x16x32_bf16(k10, qf0, s1, 0, 0, 0);
    s1 = __builtin_amdgcn_mfma_f32_16x16x32_bf16(k11, qf1, s1, 0, 0, 0);
    // s0[j] = S[q=r][kv=kv0+4g+j], s1[j] = S[q=r][kv=kv0+16+4g+j]  (pre-scale)

    float sv[8];
#pragma unroll
    for (int j = 0; j < 4; j++) { sv[j] = s0[j] * 0.125f; sv[4 + j] = s1[j] * 0.125f; }
    float tmax = sv[0];
#pragma unroll
    for (int j = 1; j < 8; j++) tmax = fmaxf(tmax, sv[j]);
    tmax = fmaxf(tmax, __shfl_xor(tmax, 16));
    tmax = fmaxf(tmax, __shfl_xor(tmax, 32));
    float mnew = fmaxf(m, tmax);
    float corr = __expf(m - mnew);

    bf16x8 pf;
    float ps = 0.0f;
#pragma unroll
    for (int j = 0; j < 8; j++) {
      float p = __expf(sv[j] - mnew);
      ps += p;
      pf[j] = f2bf(p);
    }
    ps += __shfl_xor(ps, 16);
    ps += __shfl_xor(ps, 32);
    lsum = lsum * corr + ps;
    m = mnew;
#pragma unroll
    for (int t = 0; t < 4; t++)
#pragma unroll
      for (int j = 0; j < 4; j++) o[t][j] *= corr;

    // PV: O^T tile t: a[j] = V[kv0 + 4g + (j&3) + 16*(j>>2)][16t + r]
#pragma unroll
    for (int t = 0; t < 4; t++) {
      bf16x8 vt;
#pragma unroll
      for (int j = 0; j < 8; j++) {
        int kvr = kv0 + 4 * g + (j & 3) + 16 * (j >> 2);
        vt[j] = Vp[(long)kvr * RS + 16 * t + r];
      }
      o[t] = __builtin_amdgcn_mfma_f32_16x16x32_bf16(vt, pf, o[t], 0, 0, 0);
    }
  }

  float inv = 1.0f / lsum;
  long orow = (long)(bb * NN + qbase + r) * DD + h * 64;
#pragma unroll
  for (int t = 0; t < 4; t++)
#pragma unroll
    for (int j = 0; j < 4; j++)
      attn_out[orow + 16 * t + 4 * g + j] = f2bf(o[t][j] * inv);
}

extern "C" void kernel_launch(void* const* d_in, const int* in_sizes, int n_in,
                              void* d_out, int out_size, void* d_ws, size_t ws_size,
                              hipStream_t stream) {
  const float* x = (const float*)d_in[0];
  const float* w_qkv = (const float*)d_in[1];
  const float* b_qkv = (const float*)d_in[2];
  const float* w_proj = (const float*)d_in[3];
  const float* b_proj = (const float*)d_in[4];
  float* out = (float*)d_out;

  short* ws = (short*)d_ws;
  short* xb = ws;                                // 8192*1024
  short* wqkvT = xb + (long)TOK * DD;            // 3072*1024
  short* wprojT = wqkvT + (long)QKVN * DD;       // 1024*1024
  short* qkvb = wprojT + (long)DD * DD;          // 8192*3072
  short* attn = qkvb + (long)TOK * QKVN;         // 8192*1024
  // total 46,137,344 shorts = 88 MiB of workspace

  // 1) casts
  cast_f32_bf16<<<(TOK * DD) / (256 * 4), 256, 0, stream>>>(x, xb, (long)TOK * DD);
  transpose_cast<<<dim3(QKVN / 32, DD / 32), dim3(32, 8), 0, stream>>>(w_qkv, wqkvT, DD, QKVN);
  transpose_cast<<<dim3(DD / 32, DD / 32), dim3(32, 8), 0, stream>>>(w_proj, wprojT, DD, DD);

  // 2) QKV projection: qkvb = xb @ w_qkv + b_qkv   (8192x1024 @ 1024x3072)
  gemm_bt<true><<<dim3(QKVN / 128, TOK / 128), 256, 0, stream>>>(xb, wqkvT, b_qkv, qkvb,
                                                                 TOK, QKVN, DD);

  // 3) attention: 128 (b,h) pairs x 64 q-tiles
  attn_kernel<<<dim3(NN / 16, BB * HH), 64, 0, stream>>>(qkvb, attn);

  // 4) output projection: out = attn @ w_proj + b_proj  (fp32 out)
  gemm_bt<false><<<dim3(DD / 128, TOK / 128), 256, 0, stream>>>(attn, wprojT, b_proj, out,
                                                                TOK, DD, DD);
}

// Round 2
// 294.666 us; speedup vs baseline: 1.3763x; 1.3763x over previous
//
#include <hip/hip_runtime.h>

// Problem: MultiHeadSelfAttention  B=8, N=1024, D=1024, H=16, DK=64
// x:(8,1024,1024) f32, w_qkv:(1024,3072) f32, b_qkv:(3072,), w_proj:(1024,1024), b_proj:(1024,)
// out:(8,1024,1024) f32

#define BB 8
#define NN 1024
#define DD 1024
#define HH 16
#define DK 64
#define TOK (BB * NN)        // 8192 tokens
#define QKVN (3 * DD)        // 3072

typedef __attribute__((ext_vector_type(8))) short bf16x8;
typedef __attribute__((ext_vector_type(4))) float f32x4;
typedef __attribute__((ext_vector_type(4))) short short4v;
typedef __attribute__((ext_vector_type(4))) float float4v;

static __device__ __forceinline__ short f2bf(float f) {
  union { float f; unsigned u; } v; v.f = f;
  unsigned r = (v.u + 0x7FFFu + ((v.u >> 16) & 1u)) >> 16;
  return (short)r;
}

// async global->LDS, 16B per lane. LDS dest = wave-uniform base + lane*16B.
static __device__ __forceinline__ void gload_lds16(const short* g, short* lds, int lane) {
#if __has_builtin(__builtin_amdgcn_global_load_lds)
  __builtin_amdgcn_global_load_lds((const __attribute__((address_space(1))) void*)g,
                                   (__attribute__((address_space(3))) void*)lds, 16, 0, 0);
#else
  ((bf16x8*)lds)[lane] = *(const bf16x8*)g;
#endif
}

// ---------------- cast x (f32 -> bf16), 4 elems/thread ----------------
__global__ __launch_bounds__(256) void cast_f32_bf16(const float* __restrict__ in,
                                                     short* __restrict__ out, long n) {
  long i = ((long)blockIdx.x * blockDim.x + threadIdx.x) * 4;
  if (i >= n) return;
  float4v v = *(const float4v*)(in + i);
  short4v o;
  o[0] = f2bf(v[0]); o[1] = f2bf(v[1]); o[2] = f2bf(v[2]); o[3] = f2bf(v[3]);
  *(short4v*)(out + i) = o;
}

// ------------- transpose-cast: in[rows][cols] f32 -> out[cols][rows] bf16 -------------
__global__ __launch_bounds__(256) void transpose_cast(const float* __restrict__ in,
                                                      short* __restrict__ out,
                                                      int rows, int cols) {
  __shared__ float tile[32][33];
  int bx = blockIdx.x * 32;  // col base
  int by = blockIdx.y * 32;  // row base
  int tx = threadIdx.x, ty = threadIdx.y;  // 32 x 8
#pragma unroll
  for (int q = 0; q < 4; q++)
    tile[ty + 8 * q][tx] = in[(long)(by + ty + 8 * q) * cols + bx + tx];
  __syncthreads();
#pragma unroll
  for (int q = 0; q < 4; q++)
    out[(long)(bx + ty + 8 * q) * rows + by + tx] = f2bf(tile[tx][ty + 8 * q]);
}

// ---------------- GEMM: C[M][N] = A[M][K] * Bt[N][K]^T + bias ----------------
// 128x128 tile, BK=32, 4 waves in 2x2 (64x64 each), 16x16x32 bf16 MFMA (m97 structure)
// MODE 0: fp32 out, ldc stride.
// MODE 1: bf16 out; cols < 2048 -> Cout[row][ldc=2048]; cols >= 2048 (V part) ->
//         transposed into vT[((b*16+h)*64+dk)*1024 + n] as 8B chunks (j-consecutive = n).
template <int MODE>
__global__ __launch_bounds__(256) void gemm_bt(const short* __restrict__ A,
                                               const short* __restrict__ Bt,
                                               const float* __restrict__ bias,
                                               void* __restrict__ Cout,
                                               short* __restrict__ vT,
                                               int M, int N, int K, int ldc) {
  __shared__ __align__(16) short As[128 * 32];
  __shared__ __align__(16) short Bs[128 * 32];
  const int tid = threadIdx.x;
  const int w = tid >> 6, lane = tid & 63;
  const int r = lane & 15, g = lane >> 4;
  const int wm = w >> 1, wn = w & 1;
  const long tileM = (long)blockIdx.y * 128;
  const long tileN = (long)blockIdx.x * 128;

  f32x4 acc[4][4] = {};

  const int rowInChunk = lane >> 2;       // 0..15
  const int colOff = (lane & 3) * 8;      // 0,8,16,24

  for (int k0 = 0; k0 < K; k0 += 32) {
    __syncthreads();  // previous compute done before overwriting LDS
#pragma unroll
    for (int issue = 0; issue < 2; ++issue) {
      int c = w * 2 + issue;  // chunk 0..7 = rows c*16..c*16+15
      const short* ga = A + (tileM + c * 16 + rowInChunk) * (long)K + k0 + colOff;
      gload_lds16(ga, &As[c * 512], lane);
      const short* gb = Bt + (tileN + c * 16 + rowInChunk) * (long)K + k0 + colOff;
      gload_lds16(gb, &Bs[c * 512], lane);
    }
    __syncthreads();  // staging complete (compiler drains vmcnt before barrier)

    bf16x8 a[4], b[4];
#pragma unroll
    for (int i = 0; i < 4; i++)
      a[i] = *(const bf16x8*)&As[(wm * 64 + i * 16 + r) * 32 + 8 * g];
#pragma unroll
    for (int i = 0; i < 4; i++)
      b[i] = *(const bf16x8*)&Bs[(wn * 64 + i * 16 + r) * 32 + 8 * g];
#pragma unroll
    for (int i = 0; i < 4; i++)
#pragma unroll
      for (int ii = 0; ii < 4; ii++)
        acc[i][ii] = __builtin_amdgcn_mfma_f32_16x16x32_bf16(a[i], b[ii], acc[i][ii], 0, 0, 0);
  }

  // epilogue: D layout col=lane&15, row=(lane>>4)*4+reg  [guide-verified]
#pragma unroll
  for (int i = 0; i < 4; i++) {
    long rowb = tileM + wm * 64 + i * 16 + g * 4;
#pragma unroll
    for (int ii = 0; ii < 4; ii++) {
      long cn = tileN + wn * 64 + ii * 16 + r;
      float bv = bias[cn];
      float v0 = acc[i][ii][0] + bv;
      float v1 = acc[i][ii][1] + bv;
      float v2 = acc[i][ii][2] + bv;
      float v3 = acc[i][ii][3] + bv;
      if constexpr (MODE == 0) {
        float* C = (float*)Cout;
        C[(rowb + 0) * ldc + cn] = v0;
        C[(rowb + 1) * ldc + cn] = v1;
        C[(rowb + 2) * ldc + cn] = v2;
        C[(rowb + 3) * ldc + cn] = v3;
      } else {
        if (cn < 2048) {
          short* C = (short*)Cout;
          C[(rowb + 0) * ldc + cn] = f2bf(v0);
          C[(rowb + 1) * ldc + cn] = f2bf(v1);
          C[(rowb + 2) * ldc + cn] = f2bf(v2);
          C[(rowb + 3) * ldc + cn] = f2bf(v3);
        } else {
          // V part -> vT[((b*16+h)*64+dk)*1024 + n], 4 consecutive n = 8B store
          int hc = (int)(cn - 2048);
          int b = (int)(rowb >> 10);
          long va = ((long)(b * 16 + (hc >> 6)) * 64 + (hc & 63)) * 1024 + (rowb & 1023);
          short4v sv;
          sv[0] = f2bf(v0); sv[1] = f2bf(v1); sv[2] = f2bf(v2); sv[3] = f2bf(v3);
          *(short4v*)&vT[va] = sv;
        }
      }
    }
  }
}

// ---------------- flash attention, 1 wave / block, 32 q-rows ----------------
// qk[(b*N+n)][2048]: Q cols h*64.., K cols 1024+h*64..
// vT[((b*16+h)*64+dk)*1024 + n]: V transposed per head.
// Swapped QK^T: S^T = K * Q^T -> lane owns scores for q-row (lane&15).
// PV as O^T = V^T * P^T -> rescale + output lane-local in q.
__global__ __launch_bounds__(64) void attn_kernel(const short* __restrict__ qk,
                                                  const short* __restrict__ vT,
                                                  short* __restrict__ attn_out) {
  const int bh = blockIdx.y;
  const int bb = bh >> 4, h = bh & 15;
  const int qbase = blockIdx.x * 32;
  const int lane = threadIdx.x;
  const int r = lane & 15, g = lane >> 4;
  const int RS = 2048;
  const long base = (long)bb * NN * RS;
  const short* Qp = qk + base + h * 64;
  const short* Kp = qk + base + DD + h * 64;
  const short* vTh = vT + (long)bh * 64 * 1024;

  // Q fragments: qf[qg][s]: q-row = qbase + 16*qg + r, dk = 32*s + 8g..8g+7
  bf16x8 qf[2][2];
#pragma unroll
  for (int qg = 0; qg < 2; qg++) {
    const short* qrow = Qp + (long)(qbase + 16 * qg + r) * RS;
    qf[qg][0] = *(const bf16x8*)(qrow + 8 * g);
    qf[qg][1] = *(const bf16x8*)(qrow + 32 + 8 * g);
  }

  float m[2] = {-1e30f, -1e30f}, lsum[2] = {0.0f, 0.0f};
  f32x4 o[2][4] = {};  // o[qg][t][j]: d = 16t + 4g + j, q-row = qbase+16qg+r
  bf16x8 pf[2];

  for (int kv0 = 0; kv0 < NN; kv0 += 32) {
    const short* K0 = Kp + (long)(kv0 + r) * RS;
    const short* K1 = K0 + 16 * (long)RS;
    bf16x8 k00 = *(const bf16x8*)(K0 + 8 * g);
    bf16x8 k01 = *(const bf16x8*)(K0 + 32 + 8 * g);
    bf16x8 k10 = *(const bf16x8*)(K1 + 8 * g);
    bf16x8 k11 = *(const bf16x8*)(K1 + 32 + 8 * g);

#pragma unroll
    for (int qg = 0; qg < 2; qg++) {
      f32x4 s0 = {}, s1 = {};
      s0 = __builtin_amdgcn_mfma_f32_16x16x32_bf16(k00, qf[qg][0], s0, 0, 0, 0);
      s0 = __builtin_amdgcn_mfma_f32_16x16x32_bf16(k01, qf[qg][1], s0, 0, 0, 0);
      s1 = __builtin_amdgcn_mfma_f32_16x16x32_bf16(k10, qf[qg][0], s1, 0, 0, 0);
      s1 = __builtin_amdgcn_mfma_f32_16x16x32_bf16(k11, qf[qg][1], s1, 0, 0, 0);
      // s0[j] = S[q][kv0+4g+j], s1[j] = S[q][kv0+16+4g+j]  (pre-scale)

      float sv[8];
#pragma unroll
      for (int j = 0; j < 4; j++) { sv[j] = s0[j] * 0.125f; sv[4 + j] = s1[j] * 0.125f; }
      float tmax = sv[0];
#pragma unroll
      for (int j = 1; j < 8; j++) tmax = fmaxf(tmax, sv[j]);
      tmax = fmaxf(tmax, __shfl_xor(tmax, 16));
      tmax = fmaxf(tmax, __shfl_xor(tmax, 32));
      float mnew = fmaxf(m[qg], tmax);
      float corr = __expf(m[qg] - mnew);

      float ps = 0.0f;
#pragma unroll
      for (int j = 0; j < 8; j++) {
        float p = __expf(sv[j] - mnew);
        ps += p;
        pf[qg][j] = f2bf(p);
      }
      ps += __shfl_xor(ps, 16);
      ps += __shfl_xor(ps, 32);
      lsum[qg] = lsum[qg] * corr + ps;
      m[qg] = mnew;
#pragma unroll
      for (int t = 0; t < 4; t++)
#pragma unroll
        for (int j = 0; j < 4; j++) o[qg][t][j] *= corr;
    }

    // PV: O^T tile t: vt[j] = V^T[16t+r][kv0 + 4g + (j&3) + 16*(j>>2)]
    //               = V[kv][16t+r]; shared across both q-groups.
#pragma unroll
    for (int t = 0; t < 4; t++) {
      const short* vrow = vTh + (long)(16 * t + r) * 1024 + kv0 + 4 * g;
      short4v vlo = *(const short4v*)(vrow);
      short4v vhi = *(const short4v*)(vrow + 16);
      bf16x8 vt;
#pragma unroll
      for (int j = 0; j < 4; j++) { vt[j] = vlo[j]; vt[4 + j] = vhi[j]; }
      o[0][t] = __builtin_amdgcn_mfma_f32_16x16x32_bf16(vt, pf[0], o[0][t], 0, 0, 0);
      o[1][t] = __builtin_amdgcn_mfma_f32_16x16x32_bf16(vt, pf[1], o[1][t], 0, 0, 0);
    }
  }

#pragma unroll
  for (int qg = 0; qg < 2; qg++) {
    float inv = 1.0f / lsum[qg];
    long orow = (long)(bb * NN + qbase + 16 * qg + r) * DD + h * 64;
#pragma unroll
    for (int t = 0; t < 4; t++) {
      short4v sv;
#pragma unroll
      for (int j = 0; j < 4; j++) sv[j] = f2bf(o[qg][t][j] * inv);
      *(short4v*)&attn_out[orow + 16 * t + 4 * g] = sv;
    }
  }
}

extern "C" void kernel_launch(void* const* d_in, const int* in_sizes, int n_in,
                              void* d_out, int out_size, void* d_ws, size_t ws_size,
                              hipStream_t stream) {
  const float* x = (const float*)d_in[0];
  const float* w_qkv = (const float*)d_in[1];
  const float* b_qkv = (const float*)d_in[2];
  const float* w_proj = (const float*)d_in[3];
  const float* b_proj = (const float*)d_in[4];
  float* out = (float*)d_out;

  short* ws = (short*)d_ws;
  short* xb = ws;                                // 8192*1024
  short* wqkvT = xb + (long)TOK * DD;            // 3072*1024
  short* wprojT = wqkvT + (long)QKVN * DD;       // 1024*1024
  short* qkb = wprojT + (long)DD * DD;           // 8192*2048 (Q,K only)
  short* vT = qkb + (long)TOK * 2048;            // 8192*1024 (V transposed per head)
  short* attn = vT + (long)TOK * DD;             // 8192*1024
  // total 46,137,344 shorts = 88 MiB of workspace

  // 1) casts
  cast_f32_bf16<<<(TOK * DD) / (256 * 4), 256, 0, stream>>>(x, xb, (long)TOK * DD);
  transpose_cast<<<dim3(QKVN / 32, DD / 32), dim3(32, 8), 0, stream>>>(w_qkv, wqkvT, DD, QKVN);
  transpose_cast<<<dim3(DD / 32, DD / 32), dim3(32, 8), 0, stream>>>(w_proj, wprojT, DD, DD);

  // 2) QKV projection: Q,K -> qkb[token][2048]; V -> vT (transposed per head)
  gemm_bt<1><<<dim3(QKVN / 128, TOK / 128), 256, 0, stream>>>(xb, wqkvT, b_qkv, qkb, vT,
                                                              TOK, QKVN, DD, 2048);

  // 3) attention: 32 q-tiles x 128 (b,h) pairs
  attn_kernel<<<dim3(NN / 32, BB * HH), 64, 0, stream>>>(qkb, vT, attn);

  // 4) output projection: out = attn @ w_proj + b_proj  (fp32 out)
  gemm_bt<0><<<dim3(DD / 128, TOK / 128), 256, 0, stream>>>(attn, wprojT, b_proj, out, nullptr,
                                                            TOK, DD, DD, DD);
}

// Round 3
// 293.227 us; speedup vs baseline: 1.3831x; 1.0049x over previous
//
#include <hip/hip_runtime.h>
#include <hip/hip_bf16.h>

// Problem: MultiHeadSelfAttention  B=8, N=1024, D=1024, H=16, DK=64
// x:(8,1024,1024) f32, w_qkv:(1024,3072) f32, b_qkv:(3072,), w_proj:(1024,1024), b_proj:(1024,)
// out:(8,1024,1024) f32

#define BB 8
#define NN 1024
#define DD 1024
#define HH 16
#define DK 64
#define TOK (BB * NN)        // 8192 tokens
#define QKVN (3 * DD)        // 3072

typedef __attribute__((ext_vector_type(8))) short bf16x8;
typedef __attribute__((ext_vector_type(4))) float f32x4;
typedef __attribute__((ext_vector_type(4))) short short4v;
typedef __attribute__((ext_vector_type(4))) float float4v;

// manual RNE bf16 cast (cold paths: GEMM epilogue, attn output)
static __device__ __forceinline__ short f2bf(float f) {
  union { float f; unsigned u; } v; v.f = f;
  unsigned r = (v.u + 0x7FFFu + ((v.u >> 16) & 1u)) >> 16;
  return (short)r;
}
// HIP cast (hot path: compiler recognizes & emits v_cvt_pk_bf16_f32 pairs — m240)
static __device__ __forceinline__ short f2bf_rn(float f) {
  __hip_bfloat16 h(f);
  short s;
  __builtin_memcpy(&s, &h, 2);
  return s;
}

// async global->LDS, 16B per lane. LDS dest = wave-uniform base + lane*16B.
static __device__ __forceinline__ void gload_lds16(const short* g, short* lds, int lane) {
#if __has_builtin(__builtin_amdgcn_global_load_lds)
  __builtin_amdgcn_global_load_lds((const __attribute__((address_space(1))) void*)g,
                                   (__attribute__((address_space(3))) void*)lds, 16, 0, 0);
#else
  ((bf16x8*)lds)[lane] = *(const bf16x8*)g;
#endif
}

// ---------------- cast x (f32 -> bf16), 4 elems/thread ----------------
__global__ __launch_bounds__(256) void cast_f32_bf16(const float* __restrict__ in,
                                                     short* __restrict__ out, long n) {
  long i = ((long)blockIdx.x * blockDim.x + threadIdx.x) * 4;
  if (i >= n) return;
  float4v v = *(const float4v*)(in + i);
  short4v o;
  o[0] = f2bf(v[0]); o[1] = f2bf(v[1]); o[2] = f2bf(v[2]); o[3] = f2bf(v[3]);
  *(short4v*)(out + i) = o;
}

// ------------- transpose-cast: in[rows][cols] f32 -> out[cols][rows] bf16 -------------
__global__ __launch_bounds__(256) void transpose_cast(const float* __restrict__ in,
                                                      short* __restrict__ out,
                                                      int rows, int cols) {
  __shared__ float tile[32][33];
  int bx = blockIdx.x * 32;  // col base
  int by = blockIdx.y * 32;  // row base
  int tx = threadIdx.x, ty = threadIdx.y;  // 32 x 8
#pragma unroll
  for (int q = 0; q < 4; q++)
    tile[ty + 8 * q][tx] = in[(long)(by + ty + 8 * q) * cols + bx + tx];
  __syncthreads();
#pragma unroll
  for (int q = 0; q < 4; q++)
    out[(long)(bx + ty + 8 * q) * rows + by + tx] = f2bf(tile[tx][ty + 8 * q]);
}

// ---------------- GEMM: C[M][N] = A[M][K] * Bt[N][K]^T + bias ----------------
// 128x128 tile, BK=32, 4 waves in 2x2 (64x64 each), 16x16x32 bf16 MFMA (m97 structure)
// XCD-aware block swizzle (T1): grid nwg must be divisible by 8 (true for all our launches).
// MODE 0: fp32 out, ldc stride.
// MODE 1: bf16 out; cols < 2048 -> Cout[row][ldc=2048]; cols >= 2048 (V part) ->
//         transposed into vT[((b*16+h)*64+dk)*1024 + n] as 8B chunks (j-consecutive = n).
template <int MODE>
__global__ __launch_bounds__(256) void gemm_bt(const short* __restrict__ A,
                                               const short* __restrict__ Bt,
                                               const float* __restrict__ bias,
                                               void* __restrict__ Cout,
                                               short* __restrict__ vT,
                                               int M, int N, int K, int ldc) {
  __shared__ __align__(16) short As[128 * 32];
  __shared__ __align__(16) short Bs[128 * 32];
  const int tid = threadIdx.x;
  const int w = tid >> 6, lane = tid & 63;
  const int r = lane & 15, g = lane >> 4;
  const int wm = w >> 1, wn = w & 1;

  // XCD swizzle (bijective: nwg % 8 == 0)
  const int nwg = gridDim.x * gridDim.y;
  const int flat = blockIdx.y * gridDim.x + blockIdx.x;
  const int swz = (flat & 7) * (nwg >> 3) + (flat >> 3);
  const int bx = swz % gridDim.x, by = swz / gridDim.x;

  const long tileM = (long)by * 128;
  const long tileN = (long)bx * 128;

  f32x4 acc[4][4] = {};

  const int rowInChunk = lane >> 2;       // 0..15
  const int colOff = (lane & 3) * 8;      // 0,8,16,24

  for (int k0 = 0; k0 < K; k0 += 32) {
    __syncthreads();  // previous compute done before overwriting LDS
#pragma unroll
    for (int issue = 0; issue < 2; ++issue) {
      int c = w * 2 + issue;  // chunk 0..7 = rows c*16..c*16+15
      const short* ga = A + (tileM + c * 16 + rowInChunk) * (long)K + k0 + colOff;
      gload_lds16(ga, &As[c * 512], lane);
      const short* gb = Bt + (tileN + c * 16 + rowInChunk) * (long)K + k0 + colOff;
      gload_lds16(gb, &Bs[c * 512], lane);
    }
    __syncthreads();  // staging complete (compiler drains vmcnt before barrier)

    bf16x8 a[4], b[4];
#pragma unroll
    for (int i = 0; i < 4; i++)
      a[i] = *(const bf16x8*)&As[(wm * 64 + i * 16 + r) * 32 + 8 * g];
#pragma unroll
    for (int i = 0; i < 4; i++)
      b[i] = *(const bf16x8*)&Bs[(wn * 64 + i * 16 + r) * 32 + 8 * g];
#pragma unroll
    for (int i = 0; i < 4; i++)
#pragma unroll
      for (int ii = 0; ii < 4; ii++)
        acc[i][ii] = __builtin_amdgcn_mfma_f32_16x16x32_bf16(a[i], b[ii], acc[i][ii], 0, 0, 0);
  }

  // epilogue: D layout col=lane&15, row=(lane>>4)*4+reg  [guide-verified]
#pragma unroll
  for (int i = 0; i < 4; i++) {
    long rowb = tileM + wm * 64 + i * 16 + g * 4;
#pragma unroll
    for (int ii = 0; ii < 4; ii++) {
      long cn = tileN + wn * 64 + ii * 16 + r;
      float bv = bias[cn];
      float v0 = acc[i][ii][0] + bv;
      float v1 = acc[i][ii][1] + bv;
      float v2 = acc[i][ii][2] + bv;
      float v3 = acc[i][ii][3] + bv;
      if constexpr (MODE == 0) {
        float* C = (float*)Cout;
        C[(rowb + 0) * ldc + cn] = v0;
        C[(rowb + 1) * ldc + cn] = v1;
        C[(rowb + 2) * ldc + cn] = v2;
        C[(rowb + 3) * ldc + cn] = v3;
      } else {
        if (cn < 2048) {
          short* C = (short*)Cout;
          C[(rowb + 0) * ldc + cn] = f2bf(v0);
          C[(rowb + 1) * ldc + cn] = f2bf(v1);
          C[(rowb + 2) * ldc + cn] = f2bf(v2);
          C[(rowb + 3) * ldc + cn] = f2bf(v3);
        } else {
          // V part -> vT[((b*16+h)*64+dk)*1024 + n], 4 consecutive n = 8B store
          int hc = (int)(cn - 2048);
          int b = (int)(rowb >> 10);
          long va = ((long)(b * 16 + (hc >> 6)) * 64 + (hc & 63)) * 1024 + (rowb & 1023);
          short4v sv;
          sv[0] = f2bf(v0); sv[1] = f2bf(v1); sv[2] = f2bf(v2); sv[3] = f2bf(v3);
          *(short4v*)&vT[va] = sv;
        }
      }
    }
  }
}

// ---------------- flash attention, 1 wave / block, 32 q-rows, KV=64/iter ----------------
// qk[(b*N+n)][2048]: Q cols h*64.., K cols 1024+h*64..
// vT[((b*16+h)*64+dk)*1024 + n]: V transposed per head.
// Swapped QK^T: S^T = K * Q^T -> lane owns scores for q-row (lane&15).
// PV as O^T = V^T * P^T -> rescale + output lane-local in q.
// Defer-max (T13): skip O-rescale while tile max <= m + 8 (P bounded by e^8, bf16-safe).
__global__ __launch_bounds__(64) void attn_kernel(const short* __restrict__ qk,
                                                  const short* __restrict__ vT,
                                                  short* __restrict__ attn_out) {
  // XCD swizzle keeping all 32 q-tile blocks of a head (and 4 heads) on one XCD
  const int nwg = gridDim.x * gridDim.y;  // 4096, %8==0
  const int flat = blockIdx.y * gridDim.x + blockIdx.x;
  const int swz = (flat & 7) * (nwg >> 3) + (flat >> 3);
  const int bh = swz / gridDim.x;         // (b*16+h)
  const int qbase = (swz % gridDim.x) * 32;

  const int bb = bh >> 4, h = bh & 15;
  const int lane = threadIdx.x;
  const int r = lane & 15, g = lane >> 4;
  const int RS = 2048;
  const long base = (long)bb * NN * RS;
  const short* Qp = qk + base + h * 64;
  const short* Kp = qk + base + DD + h * 64;
  const short* vTh = vT + (long)bh * 64 * 1024;

  // Q fragments: qf[qg][s]: q-row = qbase + 16*qg + r, dk = 32*s + 8g..8g+7
  bf16x8 qf[2][2];
#pragma unroll
  for (int qg = 0; qg < 2; qg++) {
    const short* qrow = Qp + (long)(qbase + 16 * qg + r) * RS;
    qf[qg][0] = *(const bf16x8*)(qrow + 8 * g);
    qf[qg][1] = *(const bf16x8*)(qrow + 32 + 8 * g);
  }

  float m[2] = {-3e38f, -3e38f}, lsum[2] = {0.0f, 0.0f};
  f32x4 o[2][4] = {};  // o[qg][t][j]: d = 16t + 4g + j, q-row = qbase+16qg+r

  for (int kv0 = 0; kv0 < NN; kv0 += 64) {
    float sv[2][16];
    // ---- QK^T for both 32-kv sub-blocks, both q-groups (16 independent MFMA) ----
#pragma unroll
    for (int c = 0; c < 2; c++) {
      const short* K0 = Kp + (long)(kv0 + 32 * c + r) * RS;
      const short* K1 = K0 + 16 * (long)RS;
      bf16x8 k00 = *(const bf16x8*)(K0 + 8 * g);
      bf16x8 k01 = *(const bf16x8*)(K0 + 32 + 8 * g);
      bf16x8 k10 = *(const bf16x8*)(K1 + 8 * g);
      bf16x8 k11 = *(const bf16x8*)(K1 + 32 + 8 * g);
#pragma unroll
      for (int qg = 0; qg < 2; qg++) {
        f32x4 s0 = {}, s1 = {};
        s0 = __builtin_amdgcn_mfma_f32_16x16x32_bf16(k00, qf[qg][0], s0, 0, 0, 0);
        s0 = __builtin_amdgcn_mfma_f32_16x16x32_bf16(k01, qf[qg][1], s0, 0, 0, 0);
        s1 = __builtin_amdgcn_mfma_f32_16x16x32_bf16(k10, qf[qg][0], s1, 0, 0, 0);
        s1 = __builtin_amdgcn_mfma_f32_16x16x32_bf16(k11, qf[qg][1], s1, 0, 0, 0);
        // s0[j] = S[q][kv0+32c+4g+j], s1[j] = S[q][kv0+32c+16+4g+j]  (pre-scale)
#pragma unroll
        for (int j = 0; j < 4; j++) {
          sv[qg][8 * c + j] = s0[j] * 0.125f;
          sv[qg][8 * c + 4 + j] = s1[j] * 0.125f;
        }
      }
    }

    // ---- online softmax (deferred rescale) ----
    bf16x8 pf[2][2];
#pragma unroll
    for (int qg = 0; qg < 2; qg++) {
      // pairwise max tree, depth 4 (+2 shfl)
      float t8[8];
#pragma unroll
      for (int j = 0; j < 8; j++) t8[j] = fmaxf(sv[qg][j], sv[qg][j + 8]);
#pragma unroll
      for (int j = 0; j < 4; j++) t8[j] = fmaxf(t8[j], t8[j + 4]);
      float tmax = fmaxf(fmaxf(t8[0], t8[1]), fmaxf(t8[2], t8[3]));
      tmax = fmaxf(tmax, __shfl_xor(tmax, 16));
      tmax = fmaxf(tmax, __shfl_xor(tmax, 32));

      if (!__all(tmax <= m[qg] + 8.0f)) {  // rare after first iter
        float mnew = fmaxf(m[qg], tmax);
        float corr = __expf(m[qg] - mnew);
#pragma unroll
        for (int t = 0; t < 4; t++)
#pragma unroll
          for (int j = 0; j < 4; j++) o[qg][t][j] *= corr;
        lsum[qg] *= corr;
        m[qg] = mnew;
      }

      float pv[16];
#pragma unroll
      for (int j = 0; j < 16; j++) pv[j] = __expf(sv[qg][j] - m[qg]);
      // pairwise sum tree
      float s8[8];
#pragma unroll
      for (int j = 0; j < 8; j++) s8[j] = pv[j] + pv[j + 8];
#pragma unroll
      for (int j = 0; j < 4; j++) s8[j] = s8[j] + s8[j + 4];
      float ps = (s8[0] + s8[1]) + (s8[2] + s8[3]);
      ps += __shfl_xor(ps, 16);
      ps += __shfl_xor(ps, 32);
      lsum[qg] += ps;
#pragma unroll
      for (int c = 0; c < 2; c++)
#pragma unroll
        for (int j = 0; j < 8; j++) pf[qg][c][j] = f2bf_rn(pv[8 * c + j]);
    }

    // ---- PV: O^T tile t, sub-block c: vt[j] = V[kv0+32c+4g+(j&3)+16*(j>>2)][16t+r] ----
#pragma unroll
    for (int t = 0; t < 4; t++) {
#pragma unroll
      for (int c = 0; c < 2; c++) {
        const short* vrow = vTh + (long)(16 * t + r) * 1024 + kv0 + 32 * c + 4 * g;
        short4v vlo = *(const short4v*)(vrow);
        short4v vhi = *(const short4v*)(vrow + 16);
        bf16x8 vt;
#pragma unroll
        for (int j = 0; j < 4; j++) { vt[j] = vlo[j]; vt[4 + j] = vhi[j]; }
        o[0][t] = __builtin_amdgcn_mfma_f32_16x16x32_bf16(vt, pf[0][c], o[0][t], 0, 0, 0);
        o[1][t] = __builtin_amdgcn_mfma_f32_16x16x32_bf16(vt, pf[1][c], o[1][t], 0, 0, 0);
      }
    }
  }

#pragma unroll
  for (int qg = 0; qg < 2; qg++) {
    float inv = 1.0f / lsum[qg];
    long orow = (long)(bb * NN + qbase + 16 * qg + r) * DD + h * 64;
#pragma unroll
    for (int t = 0; t < 4; t++) {
      short4v svv;
#pragma unroll
      for (int j = 0; j < 4; j++) svv[j] = f2bf(o[qg][t][j] * inv);
      *(short4v*)&attn_out[orow + 16 * t + 4 * g] = svv;
    }
  }
}

extern "C" void kernel_launch(void* const* d_in, const int* in_sizes, int n_in,
                              void* d_out, int out_size, void* d_ws, size_t ws_size,
                              hipStream_t stream) {
  const float* x = (const float*)d_in[0];
  const float* w_qkv = (const float*)d_in[1];
  const float* b_qkv = (const float*)d_in[2];
  const float* w_proj = (const float*)d_in[3];
  const float* b_proj = (const float*)d_in[4];
  float* out = (float*)d_out;

  short* ws = (short*)d_ws;
  short* xb = ws;                                // 8192*1024
  short* wqkvT = xb + (long)TOK * DD;            // 3072*1024
  short* wprojT = wqkvT + (long)QKVN * DD;       // 1024*1024
  short* qkb = wprojT + (long)DD * DD;           // 8192*2048 (Q,K only)
  short* vT = qkb + (long)TOK * 2048;            // 8192*1024 (V transposed per head)
  short* attn = vT + (long)TOK * DD;             // 8192*1024
  // total 46,137,344 shorts = 88 MiB of workspace

  // 1) casts
  cast_f32_bf16<<<(TOK * DD) / (256 * 4), 256, 0, stream>>>(x, xb, (long)TOK * DD);
  transpose_cast<<<dim3(QKVN / 32, DD / 32), dim3(32, 8), 0, stream>>>(w_qkv, wqkvT, DD, QKVN);
  transpose_cast<<<dim3(DD / 32, DD / 32), dim3(32, 8), 0, stream>>>(w_proj, wprojT, DD, DD);

  // 2) QKV projection: Q,K -> qkb[token][2048]; V -> vT (transposed per head)
  gemm_bt<1><<<dim3(QKVN / 128, TOK / 128), 256, 0, stream>>>(xb, wqkvT, b_qkv, qkb, vT,
                                                              TOK, QKVN, DD, 2048);

  // 3) attention: 32 q-tiles x 128 (b,h) pairs
  attn_kernel<<<dim3(NN / 32, BB * HH), 64, 0, stream>>>(qkb, vT, attn);

  // 4) output projection: out = attn @ w_proj + b_proj  (fp32 out)
  gemm_bt<0><<<dim3(DD / 128, TOK / 128), 256, 0, stream>>>(attn, wprojT, b_proj, out, nullptr,
                                                            TOK, DD, DD, DD);
}

// Round 4
// 193.128 us; speedup vs baseline: 2.0999x; 1.5183x over previous
//
#include <hip/hip_runtime.h>
#include <hip/hip_bf16.h>

// Problem: MultiHeadSelfAttention  B=8, N=1024, D=1024, H=16, DK=64
// x:(8,1024,1024) f32, w_qkv:(1024,3072) f32, b_qkv:(3072,), w_proj:(1024,1024), b_proj:(1024,)
// out:(8,1024,1024) f32

#define BB 8
#define NN 1024
#define DD 1024
#define HH 16
#define DK 64
#define TOK (BB * NN)        // 8192 tokens
#define QKVN (3 * DD)        // 3072

typedef __attribute__((ext_vector_type(8))) short bf16x8;
typedef __attribute__((ext_vector_type(4))) float f32x4;
typedef __attribute__((ext_vector_type(4))) short short4v;
typedef __attribute__((ext_vector_type(4))) float float4v;

// manual RNE bf16 cast (cold paths: GEMM epilogue, attn output)
static __device__ __forceinline__ short f2bf(float f) {
  union { float f; unsigned u; } v; v.f = f;
  unsigned r = (v.u + 0x7FFFu + ((v.u >> 16) & 1u)) >> 16;
  return (short)r;
}
// HIP cast (hot path: compiler recognizes & emits v_cvt_pk_bf16_f32 pairs — m240)
static __device__ __forceinline__ short f2bf_rn(float f) {
  __hip_bfloat16 h(f);
  short s;
  __builtin_memcpy(&s, &h, 2);
  return s;
}

// async global->LDS, 16B per lane. LDS dest = wave-uniform base + lane*16B.
static __device__ __forceinline__ void gload_lds16(const short* g, short* lds, int lane) {
#if __has_builtin(__builtin_amdgcn_global_load_lds)
  __builtin_amdgcn_global_load_lds((const __attribute__((address_space(1))) void*)g,
                                   (__attribute__((address_space(3))) void*)lds, 16, 0, 0);
#else
  ((bf16x8*)lds)[lane] = *(const bf16x8*)g;
#endif
}

// ---------------- cast x (f32 -> bf16), 4 elems/thread ----------------
__global__ __launch_bounds__(256) void cast_f32_bf16(const float* __restrict__ in,
                                                     short* __restrict__ out, long n) {
  long i = ((long)blockIdx.x * blockDim.x + threadIdx.x) * 4;
  if (i >= n) return;
  float4v v = *(const float4v*)(in + i);
  short4v o;
  o[0] = f2bf(v[0]); o[1] = f2bf(v[1]); o[2] = f2bf(v[2]); o[3] = f2bf(v[3]);
  *(short4v*)(out + i) = o;
}

// ------------- transpose-cast: in[rows][cols] f32 -> out[cols][rows] bf16 -------------
__global__ __launch_bounds__(256) void transpose_cast(const float* __restrict__ in,
                                                      short* __restrict__ out,
                                                      int rows, int cols) {
  __shared__ float tile[32][33];
  int bx = blockIdx.x * 32;  // col base
  int by = blockIdx.y * 32;  // row base
  int tx = threadIdx.x, ty = threadIdx.y;  // 32 x 8
#pragma unroll
  for (int q = 0; q < 4; q++)
    tile[ty + 8 * q][tx] = in[(long)(by + ty + 8 * q) * cols + bx + tx];
  __syncthreads();
#pragma unroll
  for (int q = 0; q < 4; q++)
    out[(long)(bx + ty + 8 * q) * rows + by + tx] = f2bf(tile[tx][ty + 8 * q]);
}

// ---------------- GEMM: C[M][N] = A[M][K] * Bt[N][K]^T + bias ----------------
// 128x128 tile, BK=32, 4 waves in 2x2 (64x64 each), 16x16x32 bf16 MFMA (m97 structure)
// XCD-aware block swizzle (T1): grid nwg must be divisible by 8 (true for all our launches).
// MODE 0: fp32 out, ldc stride.
// MODE 1: bf16 out; cols < 2048 -> Cout[row][ldc=2048]; cols >= 2048 (V part) ->
//         transposed into vT[((b*16+h)*64+dk)*1024 + n] as 8B chunks (j-consecutive = n).
template <int MODE>
__global__ __launch_bounds__(256) void gemm_bt(const short* __restrict__ A,
                                               const short* __restrict__ Bt,
                                               const float* __restrict__ bias,
                                               void* __restrict__ Cout,
                                               short* __restrict__ vT,
                                               int M, int N, int K, int ldc) {
  __shared__ __align__(16) short As[128 * 32];
  __shared__ __align__(16) short Bs[128 * 32];
  const int tid = threadIdx.x;
  const int w = tid >> 6, lane = tid & 63;
  const int r = lane & 15, g = lane >> 4;
  const int wm = w >> 1, wn = w & 1;

  // XCD swizzle (bijective: nwg % 8 == 0)
  const int nwg = gridDim.x * gridDim.y;
  const int flat = blockIdx.y * gridDim.x + blockIdx.x;
  const int swz = (flat & 7) * (nwg >> 3) + (flat >> 3);
  const int bx = swz % gridDim.x, by = swz / gridDim.x;

  const long tileM = (long)by * 128;
  const long tileN = (long)bx * 128;

  f32x4 acc[4][4] = {};

  const int rowInChunk = lane >> 2;       // 0..15
  const int colOff = (lane & 3) * 8;      // 0,8,16,24

  for (int k0 = 0; k0 < K; k0 += 32) {
    __syncthreads();  // previous compute done before overwriting LDS
#pragma unroll
    for (int issue = 0; issue < 2; ++issue) {
      int c = w * 2 + issue;  // chunk 0..7 = rows c*16..c*16+15
      const short* ga = A + (tileM + c * 16 + rowInChunk) * (long)K + k0 + colOff;
      gload_lds16(ga, &As[c * 512], lane);
      const short* gb = Bt + (tileN + c * 16 + rowInChunk) * (long)K + k0 + colOff;
      gload_lds16(gb, &Bs[c * 512], lane);
    }
    __syncthreads();  // staging complete (compiler drains vmcnt before barrier)

    bf16x8 a[4], b[4];
#pragma unroll
    for (int i = 0; i < 4; i++)
      a[i] = *(const bf16x8*)&As[(wm * 64 + i * 16 + r) * 32 + 8 * g];
#pragma unroll
    for (int i = 0; i < 4; i++)
      b[i] = *(const bf16x8*)&Bs[(wn * 64 + i * 16 + r) * 32 + 8 * g];
#pragma unroll
    for (int i = 0; i < 4; i++)
#pragma unroll
      for (int ii = 0; ii < 4; ii++)
        acc[i][ii] = __builtin_amdgcn_mfma_f32_16x16x32_bf16(a[i], b[ii], acc[i][ii], 0, 0, 0);
  }

  // epilogue: D layout col=lane&15, row=(lane>>4)*4+reg  [guide-verified]
#pragma unroll
  for (int i = 0; i < 4; i++) {
    long rowb = tileM + wm * 64 + i * 16 + g * 4;
#pragma unroll
    for (int ii = 0; ii < 4; ii++) {
      long cn = tileN + wn * 64 + ii * 16 + r;
      float bv = bias[cn];
      float v0 = acc[i][ii][0] + bv;
      float v1 = acc[i][ii][1] + bv;
      float v2 = acc[i][ii][2] + bv;
      float v3 = acc[i][ii][3] + bv;
      if constexpr (MODE == 0) {
        float* C = (float*)Cout;
        C[(rowb + 0) * ldc + cn] = v0;
        C[(rowb + 1) * ldc + cn] = v1;
        C[(rowb + 2) * ldc + cn] = v2;
        C[(rowb + 3) * ldc + cn] = v3;
      } else {
        if (cn < 2048) {
          short* C = (short*)Cout;
          C[(rowb + 0) * ldc + cn] = f2bf(v0);
          C[(rowb + 1) * ldc + cn] = f2bf(v1);
          C[(rowb + 2) * ldc + cn] = f2bf(v2);
          C[(rowb + 3) * ldc + cn] = f2bf(v3);
        } else {
          // V part -> vT[((b*16+h)*64+dk)*1024 + n], 4 consecutive n = 8B store
          int hc = (int)(cn - 2048);
          int b = (int)(rowb >> 10);
          long va = ((long)(b * 16 + (hc >> 6)) * 64 + (hc & 63)) * 1024 + (rowb & 1023);
          short4v sv;
          sv[0] = f2bf(v0); sv[1] = f2bf(v1); sv[2] = f2bf(v2); sv[3] = f2bf(v3);
          *(short4v*)&vT[va] = sv;
        }
      }
    }
  }
}

// ---------------- flash attention, 4 waves / block, 128 q-rows / block ----------------
// qk[(b*N+n)][2048]: Q cols h*64.., K cols 1024+h*64..
// vT[((b*16+h)*64+dk)*1024 + n]: V transposed per head.
// Wave w owns q rows qt*128 + 32w .. +31. K/V tiles (64 kv) staged cooperatively in LDS
// via global_load_lds (linear dest) with 16B-chunk XOR swizzle applied on the SOURCE
// address (rule #21: both-sides-or-neither), un-swizzled on the ds_read side.
// Swapped QK^T: S^T = K * Q^T -> lane owns scores for q-row (lane&15).
// PV as O^T = V^T * P^T -> rescale + output lane-local in q.
// Defer-max (T13): skip O-rescale while tile max <= m + 8 (P bounded by e^8, bf16-safe).
__global__ __launch_bounds__(256) void attn_kernel(const short* __restrict__ qk,
                                                   const short* __restrict__ vT,
                                                   short* __restrict__ attn_out) {
  // K tile [64 kv][64 dk] bf16 = 8KB, row = 128B = 8 chunks of 16B, chunk ^= (row&7)
  __shared__ __align__(16) short Ks[64 * 64];
  // V tile [64 dk][64 kv-local] bf16 = 8KB, same swizzle
  __shared__ __align__(16) short Vs[64 * 64];

  // XCD swizzle: each XCD gets 16 consecutive bh pairs (their K/V ~4MB = one L2)
  const int nwg = gridDim.x * gridDim.y;  // 1024, %8==0
  const int flat = blockIdx.y * gridDim.x + blockIdx.x;
  const int swz = (flat & 7) * (nwg >> 3) + (flat >> 3);
  const int bh = swz >> 3;                // (b*16+h)
  const int qt = swz & 7;

  const int bb = bh >> 4, h = bh & 15;
  const int tid = threadIdx.x;
  const int wid = tid >> 6, lane = tid & 63;
  const int r = lane & 15, g = lane >> 4;
  const int qbase = qt * 128 + wid * 32;
  const int RS = 2048;
  const long base = (long)bb * NN * RS;
  const short* Qp = qk + base + h * 64;
  const short* Kp = qk + base + DD + h * 64;
  const short* vTh = vT + (long)bh * 64 * 1024;

  // staging geometry: round i (0/1), wave wid covers LDS bytes [i*4096 + wid*1024 ...)
  const int srow0 = 8 * wid + (lane >> 3);       // + 32*i
  const int sj = (lane & 7) ^ (lane >> 3);       // pre-swizzled source chunk

  // Q fragments: qf[qg][s]: q-row = qbase + 16*qg + r, dk = 32*s + 8g..8g+7
  bf16x8 qf[2][2];
#pragma unroll
  for (int qg = 0; qg < 2; qg++) {
    const short* qrow = Qp + (long)(qbase + 16 * qg + r) * RS;
    qf[qg][0] = *(const bf16x8*)(qrow + 8 * g);
    qf[qg][1] = *(const bf16x8*)(qrow + 32 + 8 * g);
  }

  float m[2] = {-3e38f, -3e38f}, lsum[2] = {0.0f, 0.0f};
  f32x4 o[2][4] = {};  // o[qg][t][j]: d = 16t + 4g + j, q-row = qbase+16qg+r

  for (int kv0 = 0; kv0 < NN; kv0 += 64) {
    __syncthreads();  // previous compute's ds_reads done (compiler drains lgkmcnt)
#pragma unroll
    for (int i = 0; i < 2; i++) {
      int srow = 32 * i + srow0;
      gload_lds16(Kp + (long)(kv0 + srow) * RS + sj * 8, &Ks[i * 2048 + wid * 512], lane);
      gload_lds16(vTh + (long)srow * 1024 + kv0 + sj * 8, &Vs[i * 2048 + wid * 512], lane);
    }
    __syncthreads();  // staging complete (compiler drains vmcnt before barrier)

    // ---- K fragments from LDS: kf[c][u][s] = K[kv0+32c+16u+r][dk 32s+8g..+7] ----
    bf16x8 kf[2][2][2];
#pragma unroll
    for (int c = 0; c < 2; c++)
#pragma unroll
      for (int u = 0; u < 2; u++) {
        int krow = 32 * c + 16 * u + r;
#pragma unroll
        for (int s = 0; s < 2; s++)
          kf[c][u][s] = *(const bf16x8*)&Ks[krow * 64 + (((4 * s + g) ^ (r & 7)) * 8)];
      }

    // ---- QK^T + online softmax (deferred rescale), per q-group ----
    bf16x8 pf[2][2];
#pragma unroll
    for (int qg = 0; qg < 2; qg++) {
      f32x4 s[2][2];  // [c][u]
      __builtin_amdgcn_s_setprio(1);
#pragma unroll
      for (int c = 0; c < 2; c++)
#pragma unroll
        for (int u = 0; u < 2; u++) {
          f32x4 t = {};
          t = __builtin_amdgcn_mfma_f32_16x16x32_bf16(kf[c][u][0], qf[qg][0], t, 0, 0, 0);
          s[c][u] = __builtin_amdgcn_mfma_f32_16x16x32_bf16(kf[c][u][1], qf[qg][1], t, 0, 0, 0);
        }
      __builtin_amdgcn_s_setprio(0);

      float sv[16];
#pragma unroll
      for (int c = 0; c < 2; c++)
#pragma unroll
        for (int j = 0; j < 4; j++) {
          sv[8 * c + j] = s[c][0][j] * 0.125f;
          sv[8 * c + 4 + j] = s[c][1][j] * 0.125f;
        }

      // pairwise max tree, depth 4 (+2 shfl)
      float t8[8];
#pragma unroll
      for (int j = 0; j < 8; j++) t8[j] = fmaxf(sv[j], sv[j + 8]);
#pragma unroll
      for (int j = 0; j < 4; j++) t8[j] = fmaxf(t8[j], t8[j + 4]);
      float tmax = fmaxf(fmaxf(t8[0], t8[1]), fmaxf(t8[2], t8[3]));
      tmax = fmaxf(tmax, __shfl_xor(tmax, 16));
      tmax = fmaxf(tmax, __shfl_xor(tmax, 32));

      if (!__all(tmax <= m[qg] + 8.0f)) {  // rare after first iter
        float mnew = fmaxf(m[qg], tmax);
        float corr = __expf(m[qg] - mnew);
#pragma unroll
        for (int t = 0; t < 4; t++)
#pragma unroll
          for (int j = 0; j < 4; j++) o[qg][t][j] *= corr;
        lsum[qg] *= corr;
        m[qg] = mnew;
      }

      float pv[16];
#pragma unroll
      for (int j = 0; j < 16; j++) pv[j] = __expf(sv[j] - m[qg]);
      // pairwise sum tree
      float s8[8];
#pragma unroll
      for (int j = 0; j < 8; j++) s8[j] = pv[j] + pv[j + 8];
#pragma unroll
      for (int j = 0; j < 4; j++) s8[j] = s8[j] + s8[j + 4];
      float ps = (s8[0] + s8[1]) + (s8[2] + s8[3]);
      ps += __shfl_xor(ps, 16);
      ps += __shfl_xor(ps, 32);
      lsum[qg] += ps;
#pragma unroll
      for (int c = 0; c < 2; c++)
#pragma unroll
        for (int j = 0; j < 8; j++) pf[qg][c][j] = f2bf_rn(pv[8 * c + j]);
    }

    // ---- PV from LDS: vt[j] = V[kv0+32c+4g+(j&3)+16*(j>>2)][16t+r] ----
#pragma unroll
    for (int t = 0; t < 4; t++) {
      int vrow = 16 * t + r;
#pragma unroll
      for (int c = 0; c < 2; c++) {
        const short* vb = &Vs[vrow * 64 + (((4 * c + (g >> 1)) ^ (r & 7)) * 8) + 4 * (g & 1)];
        const short* vb2 = &Vs[vrow * 64 + (((4 * c + 2 + (g >> 1)) ^ (r & 7)) * 8) + 4 * (g & 1)];
        short4v vlo = *(const short4v*)vb;
        short4v vhi = *(const short4v*)vb2;
        bf16x8 vt;
#pragma unroll
        for (int j = 0; j < 4; j++) { vt[j] = vlo[j]; vt[4 + j] = vhi[j]; }
        __builtin_amdgcn_s_setprio(1);
        o[0][t] = __builtin_amdgcn_mfma_f32_16x16x32_bf16(vt, pf[0][c], o[0][t], 0, 0, 0);
        o[1][t] = __builtin_amdgcn_mfma_f32_16x16x32_bf16(vt, pf[1][c], o[1][t], 0, 0, 0);
        __builtin_amdgcn_s_setprio(0);
      }
    }
  }

#pragma unroll
  for (int qg = 0; qg < 2; qg++) {
    float inv = 1.0f / lsum[qg];
    long orow = (long)(bb * NN + qbase + 16 * qg + r) * DD + h * 64;
#pragma unroll
    for (int t = 0; t < 4; t++) {
      short4v svv;
#pragma unroll
      for (int j = 0; j < 4; j++) svv[j] = f2bf(o[qg][t][j] * inv);
      *(short4v*)&attn_out[orow + 16 * t + 4 * g] = svv;
    }
  }
}

extern "C" void kernel_launch(void* const* d_in, const int* in_sizes, int n_in,
                              void* d_out, int out_size, void* d_ws, size_t ws_size,
                              hipStream_t stream) {
  const float* x = (const float*)d_in[0];
  const float* w_qkv = (const float*)d_in[1];
  const float* b_qkv = (const float*)d_in[2];
  const float* w_proj = (const float*)d_in[3];
  const float* b_proj = (const float*)d_in[4];
  float* out = (float*)d_out;

  short* ws = (short*)d_ws;
  short* xb = ws;                                // 8192*1024
  short* wqkvT = xb + (long)TOK * DD;            // 3072*1024
  short* wprojT = wqkvT + (long)QKVN * DD;       // 1024*1024
  short* qkb = wprojT + (long)DD * DD;           // 8192*2048 (Q,K only)
  short* vT = qkb + (long)TOK * 2048;            // 8192*1024 (V transposed per head)
  short* attn = vT + (long)TOK * DD;             // 8192*1024
  // total 46,137,344 shorts = 88 MiB of workspace

  // 1) casts
  cast_f32_bf16<<<(TOK * DD) / (256 * 4), 256, 0, stream>>>(x, xb, (long)TOK * DD);
  transpose_cast<<<dim3(QKVN / 32, DD / 32), dim3(32, 8), 0, stream>>>(w_qkv, wqkvT, DD, QKVN);
  transpose_cast<<<dim3(DD / 32, DD / 32), dim3(32, 8), 0, stream>>>(w_proj, wprojT, DD, DD);

  // 2) QKV projection: Q,K -> qkb[token][2048]; V -> vT (transposed per head)
  gemm_bt<1><<<dim3(QKVN / 128, TOK / 128), 256, 0, stream>>>(xb, wqkvT, b_qkv, qkb, vT,
                                                              TOK, QKVN, DD, 2048);

  // 3) attention: 8 q-tiles (128 rows) x 128 (b,h) pairs, 4 waves/block
  attn_kernel<<<dim3(8, BB * HH), 256, 0, stream>>>(qkb, vT, attn);

  // 4) output projection: out = attn @ w_proj + b_proj  (fp32 out)
  gemm_bt<0><<<dim3(DD / 128, TOK / 128), 256, 0, stream>>>(attn, wprojT, b_proj, out, nullptr,
                                                            TOK, DD, DD, DD);
}

// Round 5
// 189.885 us; speedup vs baseline: 2.1358x; 1.0171x over previous
//
#include <hip/hip_runtime.h>
#include <hip/hip_bf16.h>

// Problem: MultiHeadSelfAttention  B=8, N=1024, D=1024, H=16, DK=64
// x:(8,1024,1024) f32, w_qkv:(1024,3072) f32, b_qkv:(3072,), w_proj:(1024,1024), b_proj:(1024,)
// out:(8,1024,1024) f32

#define BB 8
#define NN 1024
#define DD 1024
#define HH 16
#define DK 64
#define TOK (BB * NN)        // 8192 tokens
#define QKVN (3 * DD)        // 3072

typedef __attribute__((ext_vector_type(8))) short bf16x8;
typedef __attribute__((ext_vector_type(4))) float f32x4;
typedef __attribute__((ext_vector_type(4))) short short4v;
typedef __attribute__((ext_vector_type(4))) float float4v;

// manual RNE bf16 cast (cold paths: GEMM epilogue, attn output)
static __device__ __forceinline__ short f2bf(float f) {
  union { float f; unsigned u; } v; v.f = f;
  unsigned r = (v.u + 0x7FFFu + ((v.u >> 16) & 1u)) >> 16;
  return (short)r;
}
// HIP cast (hot path: compiler recognizes & emits v_cvt_pk_bf16_f32 pairs — m240)
static __device__ __forceinline__ short f2bf_rn(float f) {
  __hip_bfloat16 h(f);
  short s;
  __builtin_memcpy(&s, &h, 2);
  return s;
}

// async global->LDS, 16B per lane. LDS dest = wave-uniform base + lane*16B.
static __device__ __forceinline__ void gload_lds16(const short* g, short* lds, int lane) {
#if __has_builtin(__builtin_amdgcn_global_load_lds)
  __builtin_amdgcn_global_load_lds((const __attribute__((address_space(1))) void*)g,
                                   (__attribute__((address_space(3))) void*)lds, 16, 0, 0);
#else
  ((bf16x8*)lds)[lane] = *(const bf16x8*)g;
#endif
}

// ---------------- cast x (f32 -> bf16), 4 elems/thread ----------------
__global__ __launch_bounds__(256) void cast_f32_bf16(const float* __restrict__ in,
                                                     short* __restrict__ out, long n) {
  long i = ((long)blockIdx.x * blockDim.x + threadIdx.x) * 4;
  if (i >= n) return;
  float4v v = *(const float4v*)(in + i);
  short4v o;
  o[0] = f2bf(v[0]); o[1] = f2bf(v[1]); o[2] = f2bf(v[2]); o[3] = f2bf(v[3]);
  *(short4v*)(out + i) = o;
}

// ------------- transpose-cast: in[rows][cols] f32 -> out[cols][rows] bf16 -------------
__global__ __launch_bounds__(256) void transpose_cast(const float* __restrict__ in,
                                                      short* __restrict__ out,
                                                      int rows, int cols) {
  __shared__ float tile[32][33];
  int bx = blockIdx.x * 32;  // col base
  int by = blockIdx.y * 32;  // row base
  int tx = threadIdx.x, ty = threadIdx.y;  // 32 x 8
#pragma unroll
  for (int q = 0; q < 4; q++)
    tile[ty + 8 * q][tx] = in[(long)(by + ty + 8 * q) * cols + bx + tx];
  __syncthreads();
#pragma unroll
  for (int q = 0; q < 4; q++)
    out[(long)(bx + ty + 8 * q) * rows + by + tx] = f2bf(tile[tx][ty + 8 * q]);
}

// ---------------- GEMM: C[M][N] = A[M][K] * Bt[N][K]^T + bias ----------------
// 128x128 tile, BK=32, 4 waves in 2x2 (64x64 each), 16x16x32 bf16 MFMA.
// Min-2-phase pipeline (T3 recipe): double-buffered LDS; STAGE(t+1) issued BEFORE
// compute(t); single barrier per iter (compiler drains vmcnt there).
// LDS XOR swizzle (T2/rule #21): chunk ^= (row>>1)&3, applied on gload SOURCE addr
// (LDS dest stays linear) and on the ds_read address.
// XCD-aware block swizzle (T1): all our grids have nwg % 8 == 0.
// MODE 0: fp32 out, ldc stride.
// MODE 1: bf16 out; cols < 2048 -> Cout[row][ldc=2048]; cols >= 2048 (V part) ->
//         transposed into vT[((b*16+h)*64+dk)*1024 + n] as 8B chunks (j-consecutive = n).
template <int MODE>
__global__ __launch_bounds__(256) void gemm_bt(const short* __restrict__ A,
                                               const short* __restrict__ Bt,
                                               const float* __restrict__ bias,
                                               void* __restrict__ Cout,
                                               short* __restrict__ vT,
                                               int M, int N, int K, int ldc) {
  __shared__ __align__(16) short As[2][128 * 32];
  __shared__ __align__(16) short Bs[2][128 * 32];
  const int tid = threadIdx.x;
  const int w = tid >> 6, lane = tid & 63;
  const int r = lane & 15, g = lane >> 4;
  const int wm = w >> 1, wn = w & 1;

  // XCD swizzle (bijective: nwg % 8 == 0)
  const int nwg = gridDim.x * gridDim.y;
  const int flat = blockIdx.y * gridDim.x + blockIdx.x;
  const int swz = (flat & 7) * (nwg >> 3) + (flat >> 3);
  const int bx = swz % gridDim.x, by = swz / gridDim.x;

  const long tileM = (long)by * 128;
  const long tileN = (long)bx * 128;

  f32x4 acc[4][4] = {};

  // staging: wave w covers row-chunks {2w, 2w+1}; lane -> row c*16 + (lane>>2),
  // 16B chunk (lane&3). Source col pre-swizzled: chunk ^ ((row>>1)&3) = (lane&3)^((lane>>3)&3).
  const int rowInChunk = lane >> 2;
  const int colOff = ((lane & 3) ^ ((lane >> 3) & 3)) * 8;

  // read-side swizzled chunk for fragment rows (row = *16 + r): g ^ ((r>>1)&3)
  const int rdChunk = (g ^ ((r >> 1) & 3)) * 8;

  const int nt = K >> 5;
  // prologue: stage tile 0 into buf 0
#pragma unroll
  for (int issue = 0; issue < 2; ++issue) {
    int c = w * 2 + issue;
    gload_lds16(A + (tileM + c * 16 + rowInChunk) * (long)K + colOff, &As[0][c * 512], lane);
    gload_lds16(Bt + (tileN + c * 16 + rowInChunk) * (long)K + colOff, &Bs[0][c * 512], lane);
  }
  __syncthreads();  // compiler drains vmcnt before barrier

  for (int t = 0; t < nt; ++t) {
    const int cur = t & 1;
    if (t + 1 < nt) {
      const int k0 = (t + 1) << 5;
#pragma unroll
      for (int issue = 0; issue < 2; ++issue) {
        int c = w * 2 + issue;
        gload_lds16(A + (tileM + c * 16 + rowInChunk) * (long)K + k0 + colOff,
                    &As[cur ^ 1][c * 512], lane);
        gload_lds16(Bt + (tileN + c * 16 + rowInChunk) * (long)K + k0 + colOff,
                    &Bs[cur ^ 1][c * 512], lane);
      }
    }

    bf16x8 a[4], b[4];
#pragma unroll
    for (int i = 0; i < 4; i++)
      a[i] = *(const bf16x8*)&As[cur][(wm * 64 + i * 16 + r) * 32 + rdChunk];
#pragma unroll
    for (int i = 0; i < 4; i++)
      b[i] = *(const bf16x8*)&Bs[cur][(wn * 64 + i * 16 + r) * 32 + rdChunk];
#pragma unroll
    for (int i = 0; i < 4; i++)
#pragma unroll
      for (int ii = 0; ii < 4; ii++)
        acc[i][ii] = __builtin_amdgcn_mfma_f32_16x16x32_bf16(a[i], b[ii], acc[i][ii], 0, 0, 0);

    __syncthreads();  // reads of [cur] done; next iter may overwrite it
  }

  // epilogue: D layout col=lane&15, row=(lane>>4)*4+reg  [guide-verified]
#pragma unroll
  for (int i = 0; i < 4; i++) {
    long rowb = tileM + wm * 64 + i * 16 + g * 4;
#pragma unroll
    for (int ii = 0; ii < 4; ii++) {
      long cn = tileN + wn * 64 + ii * 16 + r;
      float bv = bias[cn];
      float v0 = acc[i][ii][0] + bv;
      float v1 = acc[i][ii][1] + bv;
      float v2 = acc[i][ii][2] + bv;
      float v3 = acc[i][ii][3] + bv;
      if constexpr (MODE == 0) {
        float* C = (float*)Cout;
        C[(rowb + 0) * ldc + cn] = v0;
        C[(rowb + 1) * ldc + cn] = v1;
        C[(rowb + 2) * ldc + cn] = v2;
        C[(rowb + 3) * ldc + cn] = v3;
      } else {
        if (cn < 2048) {
          short* C = (short*)Cout;
          C[(rowb + 0) * ldc + cn] = f2bf(v0);
          C[(rowb + 1) * ldc + cn] = f2bf(v1);
          C[(rowb + 2) * ldc + cn] = f2bf(v2);
          C[(rowb + 3) * ldc + cn] = f2bf(v3);
        } else {
          // V part -> vT[((b*16+h)*64+dk)*1024 + n], 4 consecutive n = 8B store
          int hc = (int)(cn - 2048);
          int b = (int)(rowb >> 10);
          long va = ((long)(b * 16 + (hc >> 6)) * 64 + (hc & 63)) * 1024 + (rowb & 1023);
          short4v sv;
          sv[0] = f2bf(v0); sv[1] = f2bf(v1); sv[2] = f2bf(v2); sv[3] = f2bf(v3);
          *(short4v*)&vT[va] = sv;
        }
      }
    }
  }
}

// ---------------- flash attention, 4 waves / block, 128 q-rows / block ----------------
// Same min-2-phase prefetch: K/V tiles double-buffered; next tile's stage issued
// before current tile's compute; one barrier per iter.
// qk[(b*N+n)][2048]: Q cols h*64.., K cols 1024+h*64..
// vT[((b*16+h)*64+dk)*1024 + n]: V transposed per head.
// Swapped QK^T: S^T = K * Q^T -> lane owns scores for q-row (lane&15).
// PV as O^T = V^T * P^T -> rescale + output lane-local in q.
// Defer-max (T13): skip O-rescale while tile max <= m + 8.
__global__ __launch_bounds__(256) void attn_kernel(const short* __restrict__ qk,
                                                   const short* __restrict__ vT,
                                                   short* __restrict__ attn_out) {
  // [64 kv][64 dk] (K) / [64 dk][64 kv] (V), row = 128B = 8 chunks, chunk ^= (row&7)
  __shared__ __align__(16) short Ks[2][64 * 64];
  __shared__ __align__(16) short Vs[2][64 * 64];

  // XCD swizzle: each XCD gets 16 consecutive bh pairs (their K/V ~4MB = one L2)
  const int nwg = gridDim.x * gridDim.y;  // 1024, %8==0
  const int flat = blockIdx.y * gridDim.x + blockIdx.x;
  const int swz = (flat & 7) * (nwg >> 3) + (flat >> 3);
  const int bh = swz >> 3;                // (b*16+h)
  const int qt = swz & 7;

  const int bb = bh >> 4, h = bh & 15;
  const int tid = threadIdx.x;
  const int wid = tid >> 6, lane = tid & 63;
  const int r = lane & 15, g = lane >> 4;
  const int qbase = qt * 128 + wid * 32;
  const int RS = 2048;
  const long base = (long)bb * NN * RS;
  const short* Qp = qk + base + h * 64;
  const short* Kp = qk + base + DD + h * 64;
  const short* vTh = vT + (long)bh * 64 * 1024;

  // staging geometry: round i (0/1), wave wid covers LDS 16B-slots [i*256 + wid*64 ...)
  const int srow0 = 8 * wid + (lane >> 3);       // + 32*i
  const int sj = (lane & 7) ^ (lane >> 3);       // pre-swizzled source chunk

  // Q fragments: qf[qg][s]: q-row = qbase + 16*qg + r, dk = 32*s + 8g..8g+7
  bf16x8 qf[2][2];
#pragma unroll
  for (int qg = 0; qg < 2; qg++) {
    const short* qrow = Qp + (long)(qbase + 16 * qg + r) * RS;
    qf[qg][0] = *(const bf16x8*)(qrow + 8 * g);
    qf[qg][1] = *(const bf16x8*)(qrow + 32 + 8 * g);
  }

  float m[2] = {-3e38f, -3e38f}, lsum[2] = {0.0f, 0.0f};
  f32x4 o[2][4] = {};  // o[qg][t][j]: d = 16t + 4g + j, q-row = qbase+16qg+r

  // prologue: stage kv tile 0 into buf 0
#pragma unroll
  for (int i = 0; i < 2; i++) {
    int srow = 32 * i + srow0;
    gload_lds16(Kp + (long)srow * RS + sj * 8, &Ks[0][i * 2048 + wid * 512], lane);
    gload_lds16(vTh + (long)srow * 1024 + sj * 8, &Vs[0][i * 2048 + wid * 512], lane);
  }
  __syncthreads();

  for (int kv0 = 0; kv0 < NN; kv0 += 64) {
    const int cur = (kv0 >> 6) & 1;
    if (kv0 + 64 < NN) {
#pragma unroll
      for (int i = 0; i < 2; i++) {
        int srow = 32 * i + srow0;
        gload_lds16(Kp + (long)(kv0 + 64 + srow) * RS + sj * 8,
                    &Ks[cur ^ 1][i * 2048 + wid * 512], lane);
        gload_lds16(vTh + (long)srow * 1024 + kv0 + 64 + sj * 8,
                    &Vs[cur ^ 1][i * 2048 + wid * 512], lane);
      }
    }

    // ---- K fragments from LDS: kf[c][u][s] = K[kv0+32c+16u+r][dk 32s+8g..+7] ----
    bf16x8 kf[2][2][2];
#pragma unroll
    for (int c = 0; c < 2; c++)
#pragma unroll
      for (int u = 0; u < 2; u++) {
        int krow = 32 * c + 16 * u + r;
#pragma unroll
        for (int s = 0; s < 2; s++)
          kf[c][u][s] = *(const bf16x8*)&Ks[cur][krow * 64 + (((4 * s + g) ^ (r & 7)) * 8)];
      }

    // ---- QK^T + online softmax (deferred rescale), per q-group ----
    bf16x8 pf[2][2];
#pragma unroll
    for (int qg = 0; qg < 2; qg++) {
      f32x4 s[2][2];  // [c][u]
      __builtin_amdgcn_s_setprio(1);
#pragma unroll
      for (int c = 0; c < 2; c++)
#pragma unroll
        for (int u = 0; u < 2; u++) {
          f32x4 t = {};
          t = __builtin_amdgcn_mfma_f32_16x16x32_bf16(kf[c][u][0], qf[qg][0], t, 0, 0, 0);
          s[c][u] = __builtin_amdgcn_mfma_f32_16x16x32_bf16(kf[c][u][1], qf[qg][1], t, 0, 0, 0);
        }
      __builtin_amdgcn_s_setprio(0);

      float sv[16];
#pragma unroll
      for (int c = 0; c < 2; c++)
#pragma unroll
        for (int j = 0; j < 4; j++) {
          sv[8 * c + j] = s[c][0][j] * 0.125f;
          sv[8 * c + 4 + j] = s[c][1][j] * 0.125f;
        }

      // pairwise max tree, depth 4 (+2 shfl)
      float t8[8];
#pragma unroll
      for (int j = 0; j < 8; j++) t8[j] = fmaxf(sv[j], sv[j + 8]);
#pragma unroll
      for (int j = 0; j < 4; j++) t8[j] = fmaxf(t8[j], t8[j + 4]);
      float tmax = fmaxf(fmaxf(t8[0], t8[1]), fmaxf(t8[2], t8[3]));
      tmax = fmaxf(tmax, __shfl_xor(tmax, 16));
      tmax = fmaxf(tmax, __shfl_xor(tmax, 32));

      if (!__all(tmax <= m[qg] + 8.0f)) {  // rare after first iter
        float mnew = fmaxf(m[qg], tmax);
        float corr = __expf(m[qg] - mnew);
#pragma unroll
        for (int t = 0; t < 4; t++)
#pragma unroll
          for (int j = 0; j < 4; j++) o[qg][t][j] *= corr;
        lsum[qg] *= corr;
        m[qg] = mnew;
      }

      float pv[16];
#pragma unroll
      for (int j = 0; j < 16; j++) pv[j] = __expf(sv[j] - m[qg]);
      // pairwise sum tree
      float s8[8];
#pragma unroll
      for (int j = 0; j < 8; j++) s8[j] = pv[j] + pv[j + 8];
#pragma unroll
      for (int j = 0; j < 4; j++) s8[j] = s8[j] + s8[j + 4];
      float ps = (s8[0] + s8[1]) + (s8[2] + s8[3]);
      ps += __shfl_xor(ps, 16);
      ps += __shfl_xor(ps, 32);
      lsum[qg] += ps;
#pragma unroll
      for (int c = 0; c < 2; c++)
#pragma unroll
        for (int j = 0; j < 8; j++) pf[qg][c][j] = f2bf_rn(pv[8 * c + j]);
    }

    // ---- PV from LDS: vt[j] = V[kv0+32c+4g+(j&3)+16*(j>>2)][16t+r] ----
#pragma unroll
    for (int t = 0; t < 4; t++) {
      int vrow = 16 * t + r;
#pragma unroll
      for (int c = 0; c < 2; c++) {
        const short* vb = &Vs[cur][vrow * 64 + (((4 * c + (g >> 1)) ^ (r & 7)) * 8) + 4 * (g & 1)];
        const short* vb2 = &Vs[cur][vrow * 64 + (((4 * c + 2 + (g >> 1)) ^ (r & 7)) * 8) + 4 * (g & 1)];
        short4v vlo = *(const short4v*)vb;
        short4v vhi = *(const short4v*)vb2;
        bf16x8 vt;
#pragma unroll
        for (int j = 0; j < 4; j++) { vt[j] = vlo[j]; vt[4 + j] = vhi[j]; }
        __builtin_amdgcn_s_setprio(1);
        o[0][t] = __builtin_amdgcn_mfma_f32_16x16x32_bf16(vt, pf[0][c], o[0][t], 0, 0, 0);
        o[1][t] = __builtin_amdgcn_mfma_f32_16x16x32_bf16(vt, pf[1][c], o[1][t], 0, 0, 0);
        __builtin_amdgcn_s_setprio(0);
      }
    }

    __syncthreads();  // reads of [cur] done; next iter may overwrite it
  }

#pragma unroll
  for (int qg = 0; qg < 2; qg++) {
    float inv = 1.0f / lsum[qg];
    long orow = (long)(bb * NN + qbase + 16 * qg + r) * DD + h * 64;
#pragma unroll
    for (int t = 0; t < 4; t++) {
      short4v svv;
#pragma unroll
      for (int j = 0; j < 4; j++) svv[j] = f2bf(o[qg][t][j] * inv);
      *(short4v*)&attn_out[orow + 16 * t + 4 * g] = svv;
    }
  }
}

extern "C" void kernel_launch(void* const* d_in, const int* in_sizes, int n_in,
                              void* d_out, int out_size, void* d_ws, size_t ws_size,
                              hipStream_t stream) {
  const float* x = (const float*)d_in[0];
  const float* w_qkv = (const float*)d_in[1];
  const float* b_qkv = (const float*)d_in[2];
  const float* w_proj = (const float*)d_in[3];
  const float* b_proj = (const float*)d_in[4];
  float* out = (float*)d_out;

  short* ws = (short*)d_ws;
  short* xb = ws;                                // 8192*1024
  short* wqkvT = xb + (long)TOK * DD;            // 3072*1024
  short* wprojT = wqkvT + (long)QKVN * DD;       // 1024*1024
  short* qkb = wprojT + (long)DD * DD;           // 8192*2048 (Q,K only)
  short* vT = qkb + (long)TOK * 2048;            // 8192*1024 (V transposed per head)
  short* attn = vT + (long)TOK * DD;             // 8192*1024
  // total 46,137,344 shorts = 88 MiB of workspace

  // 1) casts
  cast_f32_bf16<<<(TOK * DD) / (256 * 4), 256, 0, stream>>>(x, xb, (long)TOK * DD);
  transpose_cast<<<dim3(QKVN / 32, DD / 32), dim3(32, 8), 0, stream>>>(w_qkv, wqkvT, DD, QKVN);
  transpose_cast<<<dim3(DD / 32, DD / 32), dim3(32, 8), 0, stream>>>(w_proj, wprojT, DD, DD);

  // 2) QKV projection: Q,K -> qkb[token][2048]; V -> vT (transposed per head)
  gemm_bt<1><<<dim3(QKVN / 128, TOK / 128), 256, 0, stream>>>(xb, wqkvT, b_qkv, qkb, vT,
                                                              TOK, QKVN, DD, 2048);

  // 3) attention: 8 q-tiles (128 rows) x 128 (b,h) pairs, 4 waves/block
  attn_kernel<<<dim3(8, BB * HH), 256, 0, stream>>>(qkb, vT, attn);

  // 4) output projection: out = attn @ w_proj + b_proj  (fp32 out)
  gemm_bt<0><<<dim3(DD / 128, TOK / 128), 256, 0, stream>>>(attn, wprojT, b_proj, out, nullptr,
                                                            TOK, DD, DD, DD);
}

// Round 6
// 183.963 us; speedup vs baseline: 2.2045x; 1.0322x over previous
//
#include <hip/hip_runtime.h>
#include <hip/hip_bf16.h>

// Problem: MultiHeadSelfAttention  B=8, N=1024, D=1024, H=16, DK=64
// x:(8,1024,1024) f32, w_qkv:(1024,3072) f32, b_qkv:(3072,), w_proj:(1024,1024), b_proj:(1024,)
// out:(8,1024,1024) f32

#define BB 8
#define NN 1024
#define DD 1024
#define HH 16
#define DK 64
#define TOK (BB * NN)        // 8192 tokens
#define QKVN (3 * DD)        // 3072

typedef __attribute__((ext_vector_type(8))) short bf16x8;
typedef __attribute__((ext_vector_type(4))) float f32x4;
typedef __attribute__((ext_vector_type(4))) short short4v;
typedef __attribute__((ext_vector_type(4))) float float4v;

// manual RNE bf16 cast (cold paths: GEMM epilogue, attn output)
static __device__ __forceinline__ short f2bf(float f) {
  union { float f; unsigned u; } v; v.f = f;
  unsigned r = (v.u + 0x7FFFu + ((v.u >> 16) & 1u)) >> 16;
  return (short)r;
}
// HIP cast (hot path: compiler emits v_cvt_pk_bf16_f32 pairs — m240)
static __device__ __forceinline__ short f2bf_rn(float f) {
  __hip_bfloat16 h(f);
  short s;
  __builtin_memcpy(&s, &h, 2);
  return s;
}
// raw hardware exp2 (v_exp_f32 IS 2^x)
static __device__ __forceinline__ float fexp2(float x) {
#if __has_builtin(__builtin_amdgcn_exp2f)
  return __builtin_amdgcn_exp2f(x);
#else
  return __expf(x * 0.69314718056f);
#endif
}

// async global->LDS, 16B per lane. LDS dest = wave-uniform base + lane*16B.
static __device__ __forceinline__ void gload_lds16(const short* g, short* lds, int lane) {
#if __has_builtin(__builtin_amdgcn_global_load_lds)
  __builtin_amdgcn_global_load_lds((const __attribute__((address_space(1))) void*)g,
                                   (__attribute__((address_space(3))) void*)lds, 16, 0, 0);
#else
  ((bf16x8*)lds)[lane] = *(const bf16x8*)g;
#endif
}

// ---------------- cast x (f32 -> bf16), 4 elems/thread ----------------
__global__ __launch_bounds__(256) void cast_f32_bf16(const float* __restrict__ in,
                                                     short* __restrict__ out, long n) {
  long i = ((long)blockIdx.x * blockDim.x + threadIdx.x) * 4;
  if (i >= n) return;
  float4v v = *(const float4v*)(in + i);
  short4v o;
  o[0] = f2bf(v[0]); o[1] = f2bf(v[1]); o[2] = f2bf(v[2]); o[3] = f2bf(v[3]);
  *(short4v*)(out + i) = o;
}

// ------------- transpose-cast: in[rows][cols] f32 -> out[cols][rows] bf16 -------------
__global__ __launch_bounds__(256) void transpose_cast(const float* __restrict__ in,
                                                      short* __restrict__ out,
                                                      int rows, int cols) {
  __shared__ float tile[32][33];
  int bx = blockIdx.x * 32;  // col base
  int by = blockIdx.y * 32;  // row base
  int tx = threadIdx.x, ty = threadIdx.y;  // 32 x 8
#pragma unroll
  for (int q = 0; q < 4; q++)
    tile[ty + 8 * q][tx] = in[(long)(by + ty + 8 * q) * cols + bx + tx];
  __syncthreads();
#pragma unroll
  for (int q = 0; q < 4; q++)
    out[(long)(bx + ty + 8 * q) * rows + by + tx] = f2bf(tile[tx][ty + 8 * q]);
}

// ---------------- GEMM: C[M][N] = A[M][K] * Bt[N][K]^T + bias ----------------
// 128x128 tile, BK=32, 4 waves in 2x2 (64x64 each), 16x16x32 bf16 MFMA.
// Min-2-phase pipeline (T3): double-buffered LDS; STAGE(t+1) issued BEFORE compute(t).
// LDS XOR swizzle (T2/rule #21) on source + read. XCD swizzle (T1).
// MODE 0: fp32 out, ldc stride.
// MODE 1: bf16 out; cols < 2048 -> Cout[row][2048]; cols >= 2048 (V part) ->
//   vT2[((b*16+h)*64+dk)*1024 + permuted n]: within each 32-token block,
//   pos = 8*((n>>2)&3) + 4*((n>>4)&1) + (n&3)  — PV-fragment-ready order, so the
//   attention kernel loads each V fragment as ONE ds_read_b128 (no repack).
template <int MODE>
__global__ __launch_bounds__(256) void gemm_bt(const short* __restrict__ A,
                                               const short* __restrict__ Bt,
                                               const float* __restrict__ bias,
                                               void* __restrict__ Cout,
                                               short* __restrict__ vT,
                                               int M, int N, int K, int ldc) {
  __shared__ __align__(16) short As[2][128 * 32];
  __shared__ __align__(16) short Bs[2][128 * 32];
  const int tid = threadIdx.x;
  const int w = tid >> 6, lane = tid & 63;
  const int r = lane & 15, g = lane >> 4;
  const int wm = w >> 1, wn = w & 1;

  // XCD swizzle (bijective: nwg % 8 == 0)
  const int nwg = gridDim.x * gridDim.y;
  const int flat = blockIdx.y * gridDim.x + blockIdx.x;
  const int swz = (flat & 7) * (nwg >> 3) + (flat >> 3);
  const int bx = swz % gridDim.x, by = swz / gridDim.x;

  const long tileM = (long)by * 128;
  const long tileN = (long)bx * 128;

  f32x4 acc[4][4] = {};

  // staging: lane -> row c*16 + (lane>>2), 16B chunk (lane&3), source pre-swizzled
  const int rowInChunk = lane >> 2;
  const int colOff = ((lane & 3) ^ ((lane >> 3) & 3)) * 8;
  // read-side swizzled chunk for fragment rows (row = *16 + r)
  const int rdChunk = (g ^ ((r >> 1) & 3)) * 8;

  const int nt = K >> 5;
  // prologue: stage tile 0 into buf 0
#pragma unroll
  for (int issue = 0; issue < 2; ++issue) {
    int c = w * 2 + issue;
    gload_lds16(A + (tileM + c * 16 + rowInChunk) * (long)K + colOff, &As[0][c * 512], lane);
    gload_lds16(Bt + (tileN + c * 16 + rowInChunk) * (long)K + colOff, &Bs[0][c * 512], lane);
  }
  __syncthreads();  // compiler drains vmcnt before barrier

  for (int t = 0; t < nt; ++t) {
    const int cur = t & 1;
    if (t + 1 < nt) {
      const int k0 = (t + 1) << 5;
#pragma unroll
      for (int issue = 0; issue < 2; ++issue) {
        int c = w * 2 + issue;
        gload_lds16(A + (tileM + c * 16 + rowInChunk) * (long)K + k0 + colOff,
                    &As[cur ^ 1][c * 512], lane);
        gload_lds16(Bt + (tileN + c * 16 + rowInChunk) * (long)K + k0 + colOff,
                    &Bs[cur ^ 1][c * 512], lane);
      }
    }

    bf16x8 a[4], b[4];
#pragma unroll
    for (int i = 0; i < 4; i++)
      a[i] = *(const bf16x8*)&As[cur][(wm * 64 + i * 16 + r) * 32 + rdChunk];
#pragma unroll
    for (int i = 0; i < 4; i++)
      b[i] = *(const bf16x8*)&Bs[cur][(wn * 64 + i * 16 + r) * 32 + rdChunk];
#pragma unroll
    for (int i = 0; i < 4; i++)
#pragma unroll
      for (int ii = 0; ii < 4; ii++)
        acc[i][ii] = __builtin_amdgcn_mfma_f32_16x16x32_bf16(a[i], b[ii], acc[i][ii], 0, 0, 0);

    __syncthreads();  // reads of [cur] done; next iter may overwrite it
  }

  // epilogue: D layout col=lane&15, row=(lane>>4)*4+reg  [guide-verified]
#pragma unroll
  for (int i = 0; i < 4; i++) {
    long rowb = tileM + wm * 64 + i * 16 + g * 4;
#pragma unroll
    for (int ii = 0; ii < 4; ii++) {
      long cn = tileN + wn * 64 + ii * 16 + r;
      float bv = bias[cn];
      float v0 = acc[i][ii][0] + bv;
      float v1 = acc[i][ii][1] + bv;
      float v2 = acc[i][ii][2] + bv;
      float v3 = acc[i][ii][3] + bv;
      if constexpr (MODE == 0) {
        float* C = (float*)Cout;
        C[(rowb + 0) * ldc + cn] = v0;
        C[(rowb + 1) * ldc + cn] = v1;
        C[(rowb + 2) * ldc + cn] = v2;
        C[(rowb + 3) * ldc + cn] = v3;
      } else {
        if (cn < 2048) {
          short* C = (short*)Cout;
          C[(rowb + 0) * ldc + cn] = f2bf(v0);
          C[(rowb + 1) * ldc + cn] = f2bf(v1);
          C[(rowb + 2) * ldc + cn] = f2bf(v2);
          C[(rowb + 3) * ldc + cn] = f2bf(v3);
        } else {
          // V -> vT2: head-major, dk row, token permuted (fragment-ready)
          int hc = (int)(cn - 2048);             // h = hc>>6, dk = hc&63
          int b = (int)(rowb >> 10);
          int n0 = (int)(rowb & 1023);           // n0 % 4 == 0
          int pos = (n0 & ~31) + 8 * ((n0 >> 2) & 3) + 4 * ((n0 >> 4) & 1);
          long va = ((long)(b * 16 + (hc >> 6)) * 64 + (hc & 63)) * 1024 + pos;
          short4v sv;
          sv[0] = f2bf(v0); sv[1] = f2bf(v1); sv[2] = f2bf(v2); sv[3] = f2bf(v3);
          *(short4v*)&vT[va] = sv;
        }
      }
    }
  }
}

// ---------------- flash attention, 4 waves / block, 128 q-rows / block ----------------
// Single-buffer, 2 barriers/iter (empirically better than dbuf here: compiler can't
// prove gload/ds_read non-aliasing in the dbuf form and kills the overlap).
// qk[(b*N+n)][2048]: Q cols h*64.., K cols 1024+h*64..
// vT2[((b*16+h)*64+dk)*1024 + perm(n)]: V transposed per head, fragment-ready order.
// Swapped QK^T: S^T = K * Q^T -> lane owns scores for q-row (lane&15).
// PV as O^T = V^T * P^T; V A-fragment = single ds_read_b128 (perm layout).
// Softmax in exp2 domain: p = exp2(fma(s_raw, C, -m2)), C = 0.125*log2(e).
// Defer-max (T13): threshold 8 nats = 11.5416 in log2 units.
__global__ __launch_bounds__(256) void attn_kernel(const short* __restrict__ qk,
                                                   const short* __restrict__ vT,
                                                   short* __restrict__ attn_out) {
  // [64 kv][64 dk] (K) / [64 dk][64 kv-perm] (V); row = 128B = 8 chunks, chunk ^= row&7
  __shared__ __align__(16) short Ks[64 * 64];
  __shared__ __align__(16) short Vs[64 * 64];

  // XCD swizzle: each XCD gets 16 consecutive bh pairs (their K/V fit one L2)
  const int nwg = gridDim.x * gridDim.y;  // 1024, %8==0
  const int flat = blockIdx.y * gridDim.x + blockIdx.x;
  const int swz = (flat & 7) * (nwg >> 3) + (flat >> 3);
  const int bh = swz >> 3;                // (b*16+h)
  const int qt = swz & 7;

  const int bb = bh >> 4, h = bh & 15;
  const int tid = threadIdx.x;
  const int wid = tid >> 6, lane = tid & 63;
  const int r = lane & 15, g = lane >> 4;
  const int qbase = qt * 128 + wid * 32;
  const int RS = 2048;
  const long base = (long)bb * NN * RS;
  const short* Qp = qk + base + h * 64;
  const short* Kp = qk + base + DD + h * 64;
  const short* vTh = vT + (long)bh * 64 * 1024;

  // staging geometry: round i (0/1), wave wid covers rows 32i+8wid .. +7
  const int srow0 = 8 * wid + (lane >> 3);
  const int sj = (lane & 7) ^ (lane >> 3);   // pre-swizzled source chunk

  // Q fragments: qf[qg][s]: q-row = qbase + 16*qg + r, dk = 32*s + 8g..8g+7
  bf16x8 qf[2][2];
#pragma unroll
  for (int qg = 0; qg < 2; qg++) {
    const short* qrow = Qp + (long)(qbase + 16 * qg + r) * RS;
    qf[qg][0] = *(const bf16x8*)(qrow + 8 * g);
    qf[qg][1] = *(const bf16x8*)(qrow + 32 + 8 * g);
  }

  const float C = 0.18033688f;     // 0.125 * log2(e)
  float m2[2] = {-3e38f, -3e38f}, lsum[2] = {0.0f, 0.0f};
  f32x4 o[2][4] = {};  // o[qg][t][j]: d = 16t + 4g + j, q-row = qbase+16qg+r

  for (int kv0 = 0; kv0 < NN; kv0 += 64) {
    __syncthreads();  // previous compute's LDS reads done
#pragma unroll
    for (int i = 0; i < 2; i++) {
      int srow = 32 * i + srow0;
      gload_lds16(Kp + (long)(kv0 + srow) * RS + sj * 8, &Ks[i * 2048 + wid * 512], lane);
      gload_lds16(vTh + (long)srow * 1024 + kv0 + sj * 8, &Vs[i * 2048 + wid * 512], lane);
    }
    __syncthreads();  // staging complete (compiler drains vmcnt before barrier)

    // ---- K fragments: kf[c][u][s] = K[kv0+32c+16u+r][dk 32s+8g..+7] ----
    bf16x8 kf[2][2][2];
#pragma unroll
    for (int c = 0; c < 2; c++)
#pragma unroll
      for (int u = 0; u < 2; u++) {
        int krow = 32 * c + 16 * u + r;
#pragma unroll
        for (int s = 0; s < 2; s++)
          kf[c][u][s] = *(const bf16x8*)&Ks[krow * 64 + (((4 * s + g) ^ (r & 7)) * 8)];
      }

    // ---- QK^T + online softmax (exp2 domain, deferred rescale), per q-group ----
    bf16x8 pf[2][2];
#pragma unroll
    for (int qg = 0; qg < 2; qg++) {
      f32x4 s[2][2];  // [c][u]
      __builtin_amdgcn_s_setprio(1);
#pragma unroll
      for (int c = 0; c < 2; c++)
#pragma unroll
        for (int u = 0; u < 2; u++) {
          f32x4 t = {};
          t = __builtin_amdgcn_mfma_f32_16x16x32_bf16(kf[c][u][0], qf[qg][0], t, 0, 0, 0);
          s[c][u] = __builtin_amdgcn_mfma_f32_16x16x32_bf16(kf[c][u][1], qf[qg][1], t, 0, 0, 0);
        }
      __builtin_amdgcn_s_setprio(0);

      // raw scores: s16[8c+4u+j] = S[kv=kv0+32c+16u+4g+j]
      float s16[16];
#pragma unroll
      for (int c = 0; c < 2; c++)
#pragma unroll
        for (int j = 0; j < 4; j++) {
          s16[8 * c + j] = s[c][0][j];
          s16[8 * c + 4 + j] = s[c][1][j];
        }

      // pairwise max tree on RAW scores (max commutes with positive affine)
      float t8[8];
#pragma unroll
      for (int j = 0; j < 8; j++) t8[j] = fmaxf(s16[j], s16[j + 8]);
#pragma unroll
      for (int j = 0; j < 4; j++) t8[j] = fmaxf(t8[j], t8[j + 4]);
      float tmax = fmaxf(fmaxf(t8[0], t8[1]), fmaxf(t8[2], t8[3]));
      tmax = fmaxf(tmax, __shfl_xor(tmax, 16));
      tmax = fmaxf(tmax, __shfl_xor(tmax, 32));
      float tm2 = tmax * C;  // log2-domain tile max

      if (!__all(tm2 <= m2[qg] + 11.5416f)) {  // 8 nats; rare after first iter
        float mnew = fmaxf(m2[qg], tm2);
        float corr = fexp2(m2[qg] - mnew);
#pragma unroll
        for (int t = 0; t < 4; t++)
#pragma unroll
          for (int j = 0; j < 4; j++) o[qg][t][j] *= corr;
        lsum[qg] *= corr;
        m2[qg] = mnew;
      }

      float pv[16];
#pragma unroll
      for (int j = 0; j < 16; j++) pv[j] = fexp2(fmaf(s16[j], C, -m2[qg]));
      // pairwise sum tree
      float s8[8];
#pragma unroll
      for (int j = 0; j < 8; j++) s8[j] = pv[j] + pv[j + 8];
#pragma unroll
      for (int j = 0; j < 4; j++) s8[j] = s8[j] + s8[j + 4];
      float ps = (s8[0] + s8[1]) + (s8[2] + s8[3]);
      ps += __shfl_xor(ps, 16);
      ps += __shfl_xor(ps, 32);
      lsum[qg] += ps;
#pragma unroll
      for (int c = 0; c < 2; c++)
#pragma unroll
        for (int j = 0; j < 8; j++) pf[qg][c][j] = f2bf_rn(pv[8 * c + j]);
    }

    // ---- PV: per (t,c) ONE b128 read gives vt[4u+j] = V[kv0+32c+16u+4g+j][16t+r] ----
#pragma unroll
    for (int t = 0; t < 4; t++) {
      int vrow = 16 * t + r;
#pragma unroll
      for (int c = 0; c < 2; c++) {
        bf16x8 vt = *(const bf16x8*)&Vs[vrow * 64 + (((4 * c + g) ^ (r & 7)) * 8)];
        __builtin_amdgcn_s_setprio(1);
        o[0][t] = __builtin_amdgcn_mfma_f32_16x16x32_bf16(vt, pf[0][c], o[0][t], 0, 0, 0);
        o[1][t] = __builtin_amdgcn_mfma_f32_16x16x32_bf16(vt, pf[1][c], o[1][t], 0, 0, 0);
        __builtin_amdgcn_s_setprio(0);
      }
    }
  }

#pragma unroll
  for (int qg = 0; qg < 2; qg++) {
    float inv = 1.0f / lsum[qg];
    long orow = (long)(bb * NN + qbase + 16 * qg + r) * DD + h * 64;
#pragma unroll
    for (int t = 0; t < 4; t++) {
      short4v svv;
#pragma unroll
      for (int j = 0; j < 4; j++) svv[j] = f2bf(o[qg][t][j] * inv);
      *(short4v*)&attn_out[orow + 16 * t + 4 * g] = svv;
    }
  }
}

extern "C" void kernel_launch(void* const* d_in, const int* in_sizes, int n_in,
                              void* d_out, int out_size, void* d_ws, size_t ws_size,
                              hipStream_t stream) {
  const float* x = (const float*)d_in[0];
  const float* w_qkv = (const float*)d_in[1];
  const float* b_qkv = (const float*)d_in[2];
  const float* w_proj = (const float*)d_in[3];
  const float* b_proj = (const float*)d_in[4];
  float* out = (float*)d_out;

  short* ws = (short*)d_ws;
  short* xb = ws;                                // 8192*1024
  short* wqkvT = xb + (long)TOK * DD;            // 3072*1024
  short* wprojT = wqkvT + (long)QKVN * DD;       // 1024*1024
  short* qkb = wprojT + (long)DD * DD;           // 8192*2048 (Q,K only)
  short* vT = qkb + (long)TOK * 2048;            // 8192*1024 (V, head-major, perm order)
  short* attn = vT + (long)TOK * DD;             // 8192*1024
  // total 46,137,344 shorts = 88 MiB of workspace

  // 1) casts
  cast_f32_bf16<<<(TOK * DD) / (256 * 4), 256, 0, stream>>>(x, xb, (long)TOK * DD);
  transpose_cast<<<dim3(QKVN / 32, DD / 32), dim3(32, 8), 0, stream>>>(w_qkv, wqkvT, DD, QKVN);
  transpose_cast<<<dim3(DD / 32, DD / 32), dim3(32, 8), 0, stream>>>(w_proj, wprojT, DD, DD);

  // 2) QKV projection: Q,K -> qkb[token][2048]; V -> vT2 (transposed+permuted per head)
  gemm_bt<1><<<dim3(QKVN / 128, TOK / 128), 256, 0, stream>>>(xb, wqkvT, b_qkv, qkb, vT,
                                                              TOK, QKVN, DD, 2048);

  // 3) attention: 8 q-tiles (128 rows) x 128 (b,h) pairs, 4 waves/block
  attn_kernel<<<dim3(8, BB * HH), 256, 0, stream>>>(qkb, vT, attn);

  // 4) output projection: out = attn @ w_proj + b_proj  (fp32 out)
  gemm_bt<0><<<dim3(DD / 128, TOK / 128), 256, 0, stream>>>(attn, wprojT, b_proj, out, nullptr,
                                                            TOK, DD, DD, DD);
}

// Round 7
// 180.064 us; speedup vs baseline: 2.2523x; 1.0217x over previous
//
#include <hip/hip_runtime.h>
#include <hip/hip_bf16.h>

// Problem: MultiHeadSelfAttention  B=8, N=1024, D=1024, H=16, DK=64
// x:(8,1024,1024) f32, w_qkv:(1024,3072) f32, b_qkv:(3072,), w_proj:(1024,1024), b_proj:(1024,)
// out:(8,1024,1024) f32

#define BB 8
#define NN 1024
#define DD 1024
#define HH 16
#define DK 64
#define TOK (BB * NN)        // 8192 tokens
#define QKVN (3 * DD)        // 3072

typedef __attribute__((ext_vector_type(8))) short bf16x8;
typedef __attribute__((ext_vector_type(4))) float f32x4;
typedef __attribute__((ext_vector_type(4))) short short4v;
typedef __attribute__((ext_vector_type(4))) float float4v;

// manual RNE bf16 cast (cold paths)
static __device__ __forceinline__ short f2bf(float f) {
  union { float f; unsigned u; } v; v.f = f;
  unsigned r = (v.u + 0x7FFFu + ((v.u >> 16) & 1u)) >> 16;
  return (short)r;
}
// HIP cast (hot path: compiler emits v_cvt_pk_bf16_f32 pairs — m240)
static __device__ __forceinline__ short f2bf_rn(float f) {
  __hip_bfloat16 h(f);
  short s;
  __builtin_memcpy(&s, &h, 2);
  return s;
}
// raw hardware exp2 (v_exp_f32 IS 2^x)
static __device__ __forceinline__ float fexp2(float x) {
#if __has_builtin(__builtin_amdgcn_exp2f)
  return __builtin_amdgcn_exp2f(x);
#else
  return __expf(x * 0.69314718056f);
#endif
}

// async global->LDS, 16B per lane. LDS dest = wave-uniform base + lane*16B.
static __device__ __forceinline__ void gload_lds16(const short* g, short* lds, int lane) {
#if __has_builtin(__builtin_amdgcn_global_load_lds)
  __builtin_amdgcn_global_load_lds((const __attribute__((address_space(1))) void*)g,
                                   (__attribute__((address_space(3))) void*)lds, 16, 0, 0);
#else
  ((bf16x8*)lds)[lane] = *(const bf16x8*)g;
#endif
}

// raw barrier WITHOUT the implicit vmcnt(0)/lgkmcnt(0) drain of __syncthreads
// (the drain is exactly what the counted-vmcnt pipeline must avoid — T4).
static __device__ __forceinline__ void block_barrier() {
  asm volatile("" ::: "memory");
  __builtin_amdgcn_s_barrier();
  asm volatile("" ::: "memory");
}

// ---------------- cast x (f32 -> bf16), 4 elems/thread ----------------
__global__ __launch_bounds__(256) void cast_f32_bf16(const float* __restrict__ in,
                                                     short* __restrict__ out, long n) {
  long i = ((long)blockIdx.x * blockDim.x + threadIdx.x) * 4;
  if (i >= n) return;
  float4v v = *(const float4v*)(in + i);
  short4v o;
  o[0] = f2bf(v[0]); o[1] = f2bf(v[1]); o[2] = f2bf(v[2]); o[3] = f2bf(v[3]);
  *(short4v*)(out + i) = o;
}

// ------------- transpose-cast: in[rows][cols] f32 -> out[cols][rows] bf16 -------------
__global__ __launch_bounds__(256) void transpose_cast(const float* __restrict__ in,
                                                      short* __restrict__ out,
                                                      int rows, int cols) {
  __shared__ float tile[32][33];
  int bx = blockIdx.x * 32;  // col base
  int by = blockIdx.y * 32;  // row base
  int tx = threadIdx.x, ty = threadIdx.y;  // 32 x 8
#pragma unroll
  for (int q = 0; q < 4; q++)
    tile[ty + 8 * q][tx] = in[(long)(by + ty + 8 * q) * cols + bx + tx];
  __syncthreads();
#pragma unroll
  for (int q = 0; q < 4; q++)
    out[(long)(bx + ty + 8 * q) * rows + by + tx] = f2bf(tile[tx][ty + 8 * q]);
}

// ================= GEMM1: 256x256 tile, BK=64, 8-phase counted-vmcnt =================
// C[M][3072] = A[M][K] * Bt[N][K]^T + bias; Q,K cols -> qkb[token][2048]; V cols ->
// vT2 permuted (fragment-ready) layout. 8 waves (2M x 4N), per-wave C = 128x64.
// LDS: lds[dbuf2][A/B][half2][128][64] bf16 = 128 KiB. XOR swizzle chunk^=(row&7)
// both-sides (pre-swizzled gload source + swizzled ds_read). Raw s_barrier per phase;
// s_waitcnt vmcnt(4) only at phases 4/8 (tile-boundary), vmcnt(0) in last iteration.
__global__ __launch_bounds__(512, 2) void gemm256(const short* __restrict__ A,
                                                  const short* __restrict__ Bt,
                                                  const float* __restrict__ bias,
                                                  short* __restrict__ Cqk,
                                                  short* __restrict__ vT,
                                                  int M, int N, int K, int ldc) {
  __shared__ __align__(16) short lds[2][2][2][128 * 64];
  const int tid = threadIdx.x;
  const int wid = tid >> 6, lane = tid & 63;
  const int r = lane & 15, g = lane >> 4;
  const int wm = wid >> 2, wn = wid & 3;

  // XCD swizzle (bijective: nwg % 8 == 0; GEMM1 grid = 12x32 = 384)
  const int nwg = gridDim.x * gridDim.y;
  const int flat = blockIdx.y * gridDim.x + blockIdx.x;
  const int swz = (flat & 7) * (nwg >> 3) + (flat >> 3);
  const int bx = swz % gridDim.x, by = swz / gridDim.x;
  const long tileM = (long)by * 256, tileN = (long)bx * 256;

  f32x4 acc[8][4] = {};

  // staging lane geometry: instr j of wave wid covers rows wid*16+8j..+7 of a half-tile
  const int sc = ((lane & 7) ^ ((lane >> 3) & 7)) * 8;  // pre-swizzled source chunk
  const int srl = lane >> 3;                            // row-in-8-group

  // read-side swizzled chunk offsets (elements) for k-slice 0/1
  const int akc0 = ((0 + g) ^ (r & 7)) * 8;
  const int akc1 = ((4 + g) ^ (r & 7)) * 8;
  const int bn0 = (wn & 1) * 64;
  const int bh = wn >> 1;

#define STAGEA(buf, h, Tt)                                                          \
  {                                                                                 \
    _Pragma("unroll") for (int j = 0; j < 2; j++)                                   \
      gload_lds16(A + (tileM + (h) * 128 + wid * 16 + j * 8 + srl) * (long)K +      \
                      (Tt) * 64 + sc,                                               \
                  &lds[buf][0][h][(wid * 2 + j) * 512], lane);                      \
  }
#define STAGEB(buf, h, Tt)                                                          \
  {                                                                                 \
    _Pragma("unroll") for (int j = 0; j < 2; j++)                                   \
      gload_lds16(Bt + (tileN + (h) * 128 + wid * 16 + j * 8 + srl) * (long)K +     \
                      (Tt) * 64 + sc,                                               \
                  &lds[buf][1][h][(wid * 2 + j) * 512], lane);                      \
  }
#define READ_A(q, p)                                                                \
  af[0][0] = *(const bf16x8*)&lds[q][0][wm][((p) * 32 + r) * 64 + akc0];            \
  af[0][1] = *(const bf16x8*)&lds[q][0][wm][((p) * 32 + r) * 64 + akc1];            \
  af[1][0] = *(const bf16x8*)&lds[q][0][wm][((p) * 32 + 16 + r) * 64 + akc0];       \
  af[1][1] = *(const bf16x8*)&lds[q][0][wm][((p) * 32 + 16 + r) * 64 + akc1];
#define READ_B(q)                                                                   \
  {                                                                                 \
    const short* Bh = &lds[q][1][bh][0];                                            \
    _Pragma("unroll") for (int fn = 0; fn < 4; fn++) {                              \
      bf[fn][0] = *(const bf16x8*)&Bh[(bn0 + fn * 16 + r) * 64 + akc0];             \
      bf[fn][1] = *(const bf16x8*)&Bh[(bn0 + fn * 16 + r) * 64 + akc1];             \
    }                                                                               \
  }
#define MFMA_P(p)                                                                   \
  __builtin_amdgcn_s_setprio(1);                                                    \
  _Pragma("unroll") for (int fmi = 0; fmi < 2; fmi++)                               \
      _Pragma("unroll") for (int fn = 0; fn < 4; fn++) {                            \
    acc[2 * (p) + fmi][fn] = __builtin_amdgcn_mfma_f32_16x16x32_bf16(               \
        af[fmi][0], bf[fn][0], acc[2 * (p) + fmi][fn], 0, 0, 0);                    \
    acc[2 * (p) + fmi][fn] = __builtin_amdgcn_mfma_f32_16x16x32_bf16(               \
        af[fmi][1], bf[fn][1], acc[2 * (p) + fmi][fn], 0, 0, 0);                    \
  }                                                                                 \
  __builtin_amdgcn_s_setprio(0);

  const int NT = K >> 6;    // 16 K-tiles
  const int NIT = NT >> 1;  // 8 iterations (2 K-tiles each)

  // prologue: tile 0 (4 half-tiles) -> buf0; b(1) -> buf1. 12 loads/wave.
  STAGEA(0, 0, 0); STAGEA(0, 1, 0); STAGEB(0, 0, 0); STAGEB(0, 1, 0);
  STAGEB(1, 0, 1); STAGEB(1, 1, 1);
  asm volatile("s_waitcnt vmcnt(4)" ::: "memory");  // tile0 landed; b(1) may fly
  block_barrier();

  for (int i = 0; i < NIT; ++i) {
    const int t1 = 2 * i + 1, t2 = 2 * i + 2, t3 = 2 * i + 3;
    const bool full = (i < NIT - 1);
    bf16x8 af[2][2], bf[4][2];

    // ---------- K-tile 2i from buf0 (phases 0-3) ----------
    READ_A(0, 0); READ_B(0);
    STAGEA(1, 0, t1);
    block_barrier(); MFMA_P(0); block_barrier();

    READ_A(0, 1);
    STAGEA(1, 1, t1);
    block_barrier(); MFMA_P(1); block_barrier();

    READ_A(0, 2);
    if (full) STAGEB(0, 0, t2);
    block_barrier(); MFMA_P(2); block_barrier();

    READ_A(0, 3);
    if (full) STAGEB(0, 1, t2);
    if (full) asm volatile("s_waitcnt vmcnt(4)" ::: "memory");  // tile t1 landed
    else      asm volatile("s_waitcnt vmcnt(0)" ::: "memory");
    block_barrier(); MFMA_P(3); block_barrier();

    // ---------- K-tile 2i+1 from buf1 (phases 4-7) ----------
    READ_A(1, 0); READ_B(1);
    if (full) STAGEA(0, 0, t2);
    block_barrier(); MFMA_P(0); block_barrier();

    READ_A(1, 1);
    if (full) STAGEA(0, 1, t2);
    block_barrier(); MFMA_P(1); block_barrier();

    READ_A(1, 2);
    if (full) STAGEB(1, 0, t3);
    block_barrier(); MFMA_P(2); block_barrier();

    READ_A(1, 3);
    if (full) STAGEB(1, 1, t3);
    if (full) asm volatile("s_waitcnt vmcnt(4)" ::: "memory");  // tile t2 landed
    block_barrier(); MFMA_P(3); block_barrier();
  }
#undef STAGEA
#undef STAGEB
#undef READ_A
#undef READ_B
#undef MFMA_P

  // epilogue: D layout col=lane&15, row=(lane>>4)*4+reg  [guide-verified]
#pragma unroll
  for (int fm = 0; fm < 8; fm++) {
    long rowb = tileM + wm * 128 + fm * 16 + g * 4;
#pragma unroll
    for (int fn = 0; fn < 4; fn++) {
      long cn = tileN + wn * 64 + fn * 16 + r;
      float bv = bias[cn];
      float v0 = acc[fm][fn][0] + bv;
      float v1 = acc[fm][fn][1] + bv;
      float v2 = acc[fm][fn][2] + bv;
      float v3 = acc[fm][fn][3] + bv;
      if (cn < 2048) {
        Cqk[(rowb + 0) * ldc + cn] = f2bf(v0);
        Cqk[(rowb + 1) * ldc + cn] = f2bf(v1);
        Cqk[(rowb + 2) * ldc + cn] = f2bf(v2);
        Cqk[(rowb + 3) * ldc + cn] = f2bf(v3);
      } else {
        // V -> vT2: head-major, dk row, token permuted (fragment-ready)
        int hc = (int)(cn - 2048);             // h = hc>>6, dk = hc&63
        int b = (int)(rowb >> 10);
        int n0 = (int)(rowb & 1023);           // n0 % 4 == 0
        int pos = (n0 & ~31) + 8 * ((n0 >> 2) & 3) + 4 * ((n0 >> 4) & 1);
        long va = ((long)(b * 16 + (hc >> 6)) * 64 + (hc & 63)) * 1024 + pos;
        short4v sv;
        sv[0] = f2bf(v0); sv[1] = f2bf(v1); sv[2] = f2bf(v2); sv[3] = f2bf(v3);
        *(short4v*)&vT[va] = sv;
      }
    }
  }
}

// ---------------- GEMM (2-phase 128² dbuf) — used for output projection ----------------
template <int MODE>
__global__ __launch_bounds__(256) void gemm_bt(const short* __restrict__ A,
                                               const short* __restrict__ Bt,
                                               const float* __restrict__ bias,
                                               void* __restrict__ Cout,
                                               short* __restrict__ vT,
                                               int M, int N, int K, int ldc) {
  __shared__ __align__(16) short As[2][128 * 32];
  __shared__ __align__(16) short Bs[2][128 * 32];
  const int tid = threadIdx.x;
  const int w = tid >> 6, lane = tid & 63;
  const int r = lane & 15, g = lane >> 4;
  const int wm = w >> 1, wn = w & 1;

  const int nwg = gridDim.x * gridDim.y;
  const int flat = blockIdx.y * gridDim.x + blockIdx.x;
  const int swz = (flat & 7) * (nwg >> 3) + (flat >> 3);
  const int bx = swz % gridDim.x, by = swz / gridDim.x;

  const long tileM = (long)by * 128;
  const long tileN = (long)bx * 128;

  f32x4 acc[4][4] = {};

  const int rowInChunk = lane >> 2;
  const int colOff = ((lane & 3) ^ ((lane >> 3) & 3)) * 8;
  const int rdChunk = (g ^ ((r >> 1) & 3)) * 8;

  const int nt = K >> 5;
#pragma unroll
  for (int issue = 0; issue < 2; ++issue) {
    int c = w * 2 + issue;
    gload_lds16(A + (tileM + c * 16 + rowInChunk) * (long)K + colOff, &As[0][c * 512], lane);
    gload_lds16(Bt + (tileN + c * 16 + rowInChunk) * (long)K + colOff, &Bs[0][c * 512], lane);
  }
  __syncthreads();

  for (int t = 0; t < nt; ++t) {
    const int cur = t & 1;
    if (t + 1 < nt) {
      const int k0 = (t + 1) << 5;
#pragma unroll
      for (int issue = 0; issue < 2; ++issue) {
        int c = w * 2 + issue;
        gload_lds16(A + (tileM + c * 16 + rowInChunk) * (long)K + k0 + colOff,
                    &As[cur ^ 1][c * 512], lane);
        gload_lds16(Bt + (tileN + c * 16 + rowInChunk) * (long)K + k0 + colOff,
                    &Bs[cur ^ 1][c * 512], lane);
      }
    }

    bf16x8 a[4], b[4];
#pragma unroll
    for (int i = 0; i < 4; i++)
      a[i] = *(const bf16x8*)&As[cur][(wm * 64 + i * 16 + r) * 32 + rdChunk];
#pragma unroll
    for (int i = 0; i < 4; i++)
      b[i] = *(const bf16x8*)&Bs[cur][(wn * 64 + i * 16 + r) * 32 + rdChunk];
#pragma unroll
    for (int i = 0; i < 4; i++)
#pragma unroll
      for (int ii = 0; ii < 4; ii++)
        acc[i][ii] = __builtin_amdgcn_mfma_f32_16x16x32_bf16(a[i], b[ii], acc[i][ii], 0, 0, 0);

    __syncthreads();
  }

#pragma unroll
  for (int i = 0; i < 4; i++) {
    long rowb = tileM + wm * 64 + i * 16 + g * 4;
#pragma unroll
    for (int ii = 0; ii < 4; ii++) {
      long cn = tileN + wn * 64 + ii * 16 + r;
      float bv = bias[cn];
      float v0 = acc[i][ii][0] + bv;
      float v1 = acc[i][ii][1] + bv;
      float v2 = acc[i][ii][2] + bv;
      float v3 = acc[i][ii][3] + bv;
      if constexpr (MODE == 0) {
        float* C = (float*)Cout;
        C[(rowb + 0) * ldc + cn] = v0;
        C[(rowb + 1) * ldc + cn] = v1;
        C[(rowb + 2) * ldc + cn] = v2;
        C[(rowb + 3) * ldc + cn] = v3;
      } else {
        short* C = (short*)Cout;
        C[(rowb + 0) * ldc + cn] = f2bf(v0);
        C[(rowb + 1) * ldc + cn] = f2bf(v1);
        C[(rowb + 2) * ldc + cn] = f2bf(v2);
        C[(rowb + 3) * ldc + cn] = f2bf(v3);
      }
    }
  }
}

// ---------------- flash attention, 4 waves / block, 128 q-rows / block ----------------
// (unchanged from round 5 — single-buffer 2-barrier, perm-vT single-b128 PV fragments,
//  exp2-domain softmax, defer-max, XCD swizzle)
__global__ __launch_bounds__(256) void attn_kernel(const short* __restrict__ qk,
                                                   const short* __restrict__ vT,
                                                   short* __restrict__ attn_out) {
  __shared__ __align__(16) short Ks[64 * 64];
  __shared__ __align__(16) short Vs[64 * 64];

  const int nwg = gridDim.x * gridDim.y;  // 1024, %8==0
  const int flat = blockIdx.y * gridDim.x + blockIdx.x;
  const int swz = (flat & 7) * (nwg >> 3) + (flat >> 3);
  const int bh = swz >> 3;                // (b*16+h)
  const int qt = swz & 7;

  const int bb = bh >> 4, h = bh & 15;
  const int tid = threadIdx.x;
  const int wid = tid >> 6, lane = tid & 63;
  const int r = lane & 15, g = lane >> 4;
  const int qbase = qt * 128 + wid * 32;
  const int RS = 2048;
  const long base = (long)bb * NN * RS;
  const short* Qp = qk + base + h * 64;
  const short* Kp = qk + base + DD + h * 64;
  const short* vTh = vT + (long)bh * 64 * 1024;

  const int srow0 = 8 * wid + (lane >> 3);
  const int sj = (lane & 7) ^ (lane >> 3);   // pre-swizzled source chunk

  bf16x8 qf[2][2];
#pragma unroll
  for (int qg = 0; qg < 2; qg++) {
    const short* qrow = Qp + (long)(qbase + 16 * qg + r) * RS;
    qf[qg][0] = *(const bf16x8*)(qrow + 8 * g);
    qf[qg][1] = *(const bf16x8*)(qrow + 32 + 8 * g);
  }

  const float C = 0.18033688f;     // 0.125 * log2(e)
  float m2[2] = {-3e38f, -3e38f}, lsum[2] = {0.0f, 0.0f};
  f32x4 o[2][4] = {};

  for (int kv0 = 0; kv0 < NN; kv0 += 64) {
    __syncthreads();
#pragma unroll
    for (int i = 0; i < 2; i++) {
      int srow = 32 * i + srow0;
      gload_lds16(Kp + (long)(kv0 + srow) * RS + sj * 8, &Ks[i * 2048 + wid * 512], lane);
      gload_lds16(vTh + (long)srow * 1024 + kv0 + sj * 8, &Vs[i * 2048 + wid * 512], lane);
    }
    __syncthreads();

    bf16x8 kf[2][2][2];
#pragma unroll
    for (int c = 0; c < 2; c++)
#pragma unroll
      for (int u = 0; u < 2; u++) {
        int krow = 32 * c + 16 * u + r;
#pragma unroll
        for (int s = 0; s < 2; s++)
          kf[c][u][s] = *(const bf16x8*)&Ks[krow * 64 + (((4 * s + g) ^ (r & 7)) * 8)];
      }

    bf16x8 pf[2][2];
#pragma unroll
    for (int qg = 0; qg < 2; qg++) {
      f32x4 s[2][2];
      __builtin_amdgcn_s_setprio(1);
#pragma unroll
      for (int c = 0; c < 2; c++)
#pragma unroll
        for (int u = 0; u < 2; u++) {
          f32x4 t = {};
          t = __builtin_amdgcn_mfma_f32_16x16x32_bf16(kf[c][u][0], qf[qg][0], t, 0, 0, 0);
          s[c][u] = __builtin_amdgcn_mfma_f32_16x16x32_bf16(kf[c][u][1], qf[qg][1], t, 0, 0, 0);
        }
      __builtin_amdgcn_s_setprio(0);

      float s16[16];
#pragma unroll
      for (int c = 0; c < 2; c++)
#pragma unroll
        for (int j = 0; j < 4; j++) {
          s16[8 * c + j] = s[c][0][j];
          s16[8 * c + 4 + j] = s[c][1][j];
        }

      float t8[8];
#pragma unroll
      for (int j = 0; j < 8; j++) t8[j] = fmaxf(s16[j], s16[j + 8]);
#pragma unroll
      for (int j = 0; j < 4; j++) t8[j] = fmaxf(t8[j], t8[j + 4]);
      float tmax = fmaxf(fmaxf(t8[0], t8[1]), fmaxf(t8[2], t8[3]));
      tmax = fmaxf(tmax, __shfl_xor(tmax, 16));
      tmax = fmaxf(tmax, __shfl_xor(tmax, 32));
      float tm2 = tmax * C;

      if (!__all(tm2 <= m2[qg] + 11.5416f)) {
        float mnew = fmaxf(m2[qg], tm2);
        float corr = fexp2(m2[qg] - mnew);
#pragma unroll
        for (int t = 0; t < 4; t++)
#pragma unroll
          for (int j = 0; j < 4; j++) o[qg][t][j] *= corr;
        lsum[qg] *= corr;
        m2[qg] = mnew;
      }

      float pv[16];
#pragma unroll
      for (int j = 0; j < 16; j++) pv[j] = fexp2(fmaf(s16[j], C, -m2[qg]));
      float s8[8];
#pragma unroll
      for (int j = 0; j < 8; j++) s8[j] = pv[j] + pv[j + 8];
#pragma unroll
      for (int j = 0; j < 4; j++) s8[j] = s8[j] + s8[j + 4];
      float ps = (s8[0] + s8[1]) + (s8[2] + s8[3]);
      ps += __shfl_xor(ps, 16);
      ps += __shfl_xor(ps, 32);
      lsum[qg] += ps;
#pragma unroll
      for (int c = 0; c < 2; c++)
#pragma unroll
        for (int j = 0; j < 8; j++) pf[qg][c][j] = f2bf_rn(pv[8 * c + j]);
    }

#pragma unroll
    for (int t = 0; t < 4; t++) {
      int vrow = 16 * t + r;
#pragma unroll
      for (int c = 0; c < 2; c++) {
        bf16x8 vt = *(const bf16x8*)&Vs[vrow * 64 + (((4 * c + g) ^ (r & 7)) * 8)];
        __builtin_amdgcn_s_setprio(1);
        o[0][t] = __builtin_amdgcn_mfma_f32_16x16x32_bf16(vt, pf[0][c], o[0][t], 0, 0, 0);
        o[1][t] = __builtin_amdgcn_mfma_f32_16x16x32_bf16(vt, pf[1][c], o[1][t], 0, 0, 0);
        __builtin_amdgcn_s_setprio(0);
      }
    }
  }

#pragma unroll
  for (int qg = 0; qg < 2; qg++) {
    float inv = 1.0f / lsum[qg];
    long orow = (long)(bb * NN + qbase + 16 * qg + r) * DD + h * 64;
#pragma unroll
    for (int t = 0; t < 4; t++) {
      short4v svv;
#pragma unroll
      for (int j = 0; j < 4; j++) svv[j] = f2bf(o[qg][t][j] * inv);
      *(short4v*)&attn_out[orow + 16 * t + 4 * g] = svv;
    }
  }
}

extern "C" void kernel_launch(void* const* d_in, const int* in_sizes, int n_in,
                              void* d_out, int out_size, void* d_ws, size_t ws_size,
                              hipStream_t stream) {
  const float* x = (const float*)d_in[0];
  const float* w_qkv = (const float*)d_in[1];
  const float* b_qkv = (const float*)d_in[2];
  const float* w_proj = (const float*)d_in[3];
  const float* b_proj = (const float*)d_in[4];
  float* out = (float*)d_out;

  short* ws = (short*)d_ws;
  short* xb = ws;                                // 8192*1024
  short* wqkvT = xb + (long)TOK * DD;            // 3072*1024
  short* wprojT = wqkvT + (long)QKVN * DD;       // 1024*1024
  short* qkb = wprojT + (long)DD * DD;           // 8192*2048 (Q,K only)
  short* vT = qkb + (long)TOK * 2048;            // 8192*1024 (V, head-major, perm order)
  short* attn = vT + (long)TOK * DD;             // 8192*1024
  // total 46,137,344 shorts = 88 MiB of workspace

  // 1) casts
  cast_f32_bf16<<<(TOK * DD) / (256 * 4), 256, 0, stream>>>(x, xb, (long)TOK * DD);
  transpose_cast<<<dim3(QKVN / 32, DD / 32), dim3(32, 8), 0, stream>>>(w_qkv, wqkvT, DD, QKVN);
  transpose_cast<<<dim3(DD / 32, DD / 32), dim3(32, 8), 0, stream>>>(w_proj, wprojT, DD, DD);

  // 2) QKV projection (256² 8-phase): Q,K -> qkb; V -> vT2 (transposed+permuted per head)
  gemm256<<<dim3(QKVN / 256, TOK / 256), 512, 0, stream>>>(xb, wqkvT, b_qkv, qkb, vT,
                                                           TOK, QKVN, DD, 2048);

  // 3) attention: 8 q-tiles (128 rows) x 128 (b,h) pairs, 4 waves/block
  attn_kernel<<<dim3(8, BB * HH), 256, 0, stream>>>(qkb, vT, attn);

  // 4) output projection: out = attn @ w_proj + b_proj  (fp32 out)
  gemm_bt<0><<<dim3(DD / 128, TOK / 128), 256, 0, stream>>>(attn, wprojT, b_proj, out, nullptr,
                                                            TOK, DD, DD, DD);
}

// Round 8
// 176.584 us; speedup vs baseline: 2.2967x; 1.0197x over previous
//
#include <hip/hip_runtime.h>
#include <hip/hip_bf16.h>

// Problem: MultiHeadSelfAttention  B=8, N=1024, D=1024, H=16, DK=64
// x:(8,1024,1024) f32, w_qkv:(1024,3072) f32, b_qkv:(3072,), w_proj:(1024,1024), b_proj:(1024,)
// out:(8,1024,1024) f32

#define BB 8
#define NN 1024
#define DD 1024
#define HH 16
#define DK 64
#define TOK (BB * NN)        // 8192 tokens
#define QKVN (3 * DD)        // 3072

typedef __attribute__((ext_vector_type(8))) short bf16x8;
typedef __attribute__((ext_vector_type(4))) float f32x4;
typedef __attribute__((ext_vector_type(4))) short short4v;
typedef __attribute__((ext_vector_type(4))) float float4v;

// manual RNE bf16 cast (cold paths)
static __device__ __forceinline__ short f2bf(float f) {
  union { float f; unsigned u; } v; v.f = f;
  unsigned r = (v.u + 0x7FFFu + ((v.u >> 16) & 1u)) >> 16;
  return (short)r;
}
// HIP cast (hot path: compiler emits v_cvt_pk_bf16_f32 pairs — m240)
static __device__ __forceinline__ short f2bf_rn(float f) {
  __hip_bfloat16 h(f);
  short s;
  __builtin_memcpy(&s, &h, 2);
  return s;
}
// raw hardware exp2 (v_exp_f32 IS 2^x)
static __device__ __forceinline__ float fexp2(float x) {
#if __has_builtin(__builtin_amdgcn_exp2f)
  return __builtin_amdgcn_exp2f(x);
#else
  return __expf(x * 0.69314718056f);
#endif
}

// async global->LDS, 16B per lane. LDS dest = wave-uniform base + lane*16B.
static __device__ __forceinline__ void gload_lds16(const short* g, short* lds, int lane) {
#if __has_builtin(__builtin_amdgcn_global_load_lds)
  __builtin_amdgcn_global_load_lds((const __attribute__((address_space(1))) void*)g,
                                   (__attribute__((address_space(3))) void*)lds, 16, 0, 0);
#else
  ((bf16x8*)lds)[lane] = *(const bf16x8*)g;
#endif
}

// raw barrier WITHOUT the implicit vmcnt(0)/lgkmcnt(0) drain of __syncthreads (T4).
static __device__ __forceinline__ void block_barrier() {
  asm volatile("" ::: "memory");
  __builtin_amdgcn_s_barrier();
  asm volatile("" ::: "memory");
}

// ---------------- cast x (f32 -> bf16), 4 elems/thread ----------------
__global__ __launch_bounds__(256) void cast_f32_bf16(const float* __restrict__ in,
                                                     short* __restrict__ out, long n) {
  long i = ((long)blockIdx.x * blockDim.x + threadIdx.x) * 4;
  if (i >= n) return;
  float4v v = *(const float4v*)(in + i);
  short4v o;
  o[0] = f2bf(v[0]); o[1] = f2bf(v[1]); o[2] = f2bf(v[2]); o[3] = f2bf(v[3]);
  *(short4v*)(out + i) = o;
}

// ------------- transpose-cast: in[rows][cols] f32 -> out[cols][rows] bf16 -------------
__global__ __launch_bounds__(256) void transpose_cast(const float* __restrict__ in,
                                                      short* __restrict__ out,
                                                      int rows, int cols) {
  __shared__ float tile[32][33];
  int bx = blockIdx.x * 32;  // col base
  int by = blockIdx.y * 32;  // row base
  int tx = threadIdx.x, ty = threadIdx.y;  // 32 x 8
#pragma unroll
  for (int q = 0; q < 4; q++)
    tile[ty + 8 * q][tx] = in[(long)(by + ty + 8 * q) * cols + bx + tx];
  __syncthreads();
#pragma unroll
  for (int q = 0; q < 4; q++)
    out[(long)(bx + ty + 8 * q) * rows + by + tx] = f2bf(tile[tx][ty + 8 * q]);
}

// ================= QK projection: 256x256 tile, BK=64, 8-phase counted-vmcnt ==========
// qkb[M][2048] = A[M][K] * Bt[0..2047][K]^T + bias. N=2048 -> grid 8x32 = 256 blocks =
// EXACTLY one round (1 block/CU, 128 KiB LDS). 8 waves (2M x 4N), per-wave C = 128x64.
// Phase recipe per m201: {ds_read subtile || stage half-tile} -> s_barrier ->
// s_waitcnt lgkmcnt(0) -> sched_barrier(0) -> setprio(1) 16xMFMA setprio(0) -> s_barrier.
// vmcnt(4) only at tile boundaries (phases 4/8), vmcnt(0) in last iteration.
__global__ __launch_bounds__(512, 2) void gemm256(const short* __restrict__ A,
                                                  const short* __restrict__ Bt,
                                                  const float* __restrict__ bias,
                                                  short* __restrict__ Cqk,
                                                  int M, int N, int K, int ldc) {
  __shared__ __align__(16) short lds[2][2][2][128 * 64];
  const int tid = threadIdx.x;
  const int wid = tid >> 6, lane = tid & 63;
  const int r = lane & 15, g = lane >> 4;
  const int wm = wid >> 2, wn = wid & 3;

  // XCD swizzle (bijective: nwg % 8 == 0; grid = 8x32 = 256)
  const int nwg = gridDim.x * gridDim.y;
  const int flat = blockIdx.y * gridDim.x + blockIdx.x;
  const int swz = (flat & 7) * (nwg >> 3) + (flat >> 3);
  const int bx = swz % gridDim.x, by = swz / gridDim.x;
  const long tileM = (long)by * 256, tileN = (long)bx * 256;

  f32x4 acc[8][4] = {};

  // staging lane geometry: instr j of wave wid covers rows wid*16+8j..+7 of a half-tile
  const int sc = ((lane & 7) ^ ((lane >> 3) & 7)) * 8;  // pre-swizzled source chunk
  const int srl = lane >> 3;                            // row-in-8-group

  // read-side swizzled chunk offsets (elements) for k-slice 0/1
  const int akc0 = ((0 + g) ^ (r & 7)) * 8;
  const int akc1 = ((4 + g) ^ (r & 7)) * 8;
  const int bn0 = (wn & 1) * 64;
  const int bhh = wn >> 1;

#define STAGEA(buf, h, Tt)                                                          \
  {                                                                                 \
    _Pragma("unroll") for (int j = 0; j < 2; j++)                                   \
      gload_lds16(A + (tileM + (h) * 128 + wid * 16 + j * 8 + srl) * (long)K +      \
                      (Tt) * 64 + sc,                                               \
                  &lds[buf][0][h][(wid * 2 + j) * 512], lane);                      \
  }
#define STAGEB(buf, h, Tt)                                                          \
  {                                                                                 \
    _Pragma("unroll") for (int j = 0; j < 2; j++)                                   \
      gload_lds16(Bt + (tileN + (h) * 128 + wid * 16 + j * 8 + srl) * (long)K +     \
                      (Tt) * 64 + sc,                                               \
                  &lds[buf][1][h][(wid * 2 + j) * 512], lane);                      \
  }
#define READ_A(q, p)                                                                \
  af[0][0] = *(const bf16x8*)&lds[q][0][wm][((p) * 32 + r) * 64 + akc0];            \
  af[0][1] = *(const bf16x8*)&lds[q][0][wm][((p) * 32 + r) * 64 + akc1];            \
  af[1][0] = *(const bf16x8*)&lds[q][0][wm][((p) * 32 + 16 + r) * 64 + akc0];       \
  af[1][1] = *(const bf16x8*)&lds[q][0][wm][((p) * 32 + 16 + r) * 64 + akc1];
#define READ_B(q)                                                                   \
  {                                                                                 \
    const short* Bh = &lds[q][1][bhh][0];                                           \
    _Pragma("unroll") for (int fn = 0; fn < 4; fn++) {                              \
      bf[fn][0] = *(const bf16x8*)&Bh[(bn0 + fn * 16 + r) * 64 + akc0];             \
      bf[fn][1] = *(const bf16x8*)&Bh[(bn0 + fn * 16 + r) * 64 + akc1];             \
    }                                                                               \
  }
// post-barrier burst discipline (m201 template): all LDS reads done, pin order.
#define WAITL()                                                                     \
  asm volatile("s_waitcnt lgkmcnt(0)" ::: "memory");                                \
  __builtin_amdgcn_sched_barrier(0);
#define MFMA_P(p)                                                                   \
  __builtin_amdgcn_s_setprio(1);                                                    \
  _Pragma("unroll") for (int fmi = 0; fmi < 2; fmi++)                               \
      _Pragma("unroll") for (int fn = 0; fn < 4; fn++) {                            \
    acc[2 * (p) + fmi][fn] = __builtin_amdgcn_mfma_f32_16x16x32_bf16(               \
        af[fmi][0], bf[fn][0], acc[2 * (p) + fmi][fn], 0, 0, 0);                    \
    acc[2 * (p) + fmi][fn] = __builtin_amdgcn_mfma_f32_16x16x32_bf16(               \
        af[fmi][1], bf[fn][1], acc[2 * (p) + fmi][fn], 0, 0, 0);                    \
  }                                                                                 \
  __builtin_amdgcn_s_setprio(0);

  const int NT = K >> 6;    // 16 K-tiles
  const int NIT = NT >> 1;  // 8 iterations (2 K-tiles each)

  // prologue: tile 0 (4 half-tiles) -> buf0; b(1) -> buf1. 12 loads/wave.
  STAGEA(0, 0, 0); STAGEA(0, 1, 0); STAGEB(0, 0, 0); STAGEB(0, 1, 0);
  STAGEB(1, 0, 1); STAGEB(1, 1, 1);
  asm volatile("s_waitcnt vmcnt(4)" ::: "memory");  // tile0 landed; b(1) may fly
  block_barrier();

  for (int i = 0; i < NIT; ++i) {
    const int t1 = 2 * i + 1, t2 = 2 * i + 2, t3 = 2 * i + 3;
    const bool full = (i < NIT - 1);
    bf16x8 af[2][2], bf[4][2];

    // ---------- K-tile 2i from buf0 (phases 0-3) ----------
    READ_A(0, 0); READ_B(0);
    STAGEA(1, 0, t1);
    block_barrier(); WAITL(); MFMA_P(0); block_barrier();

    READ_A(0, 1);
    STAGEA(1, 1, t1);
    block_barrier(); WAITL(); MFMA_P(1); block_barrier();

    READ_A(0, 2);
    if (full) STAGEB(0, 0, t2);
    block_barrier(); WAITL(); MFMA_P(2); block_barrier();

    READ_A(0, 3);
    if (full) STAGEB(0, 1, t2);
    if (full) asm volatile("s_waitcnt vmcnt(4)" ::: "memory");  // tile t1 landed
    else      asm volatile("s_waitcnt vmcnt(0)" ::: "memory");
    block_barrier(); WAITL(); MFMA_P(3); block_barrier();

    // ---------- K-tile 2i+1 from buf1 (phases 4-7) ----------
    READ_A(1, 0); READ_B(1);
    if (full) STAGEA(0, 0, t2);
    block_barrier(); WAITL(); MFMA_P(0); block_barrier();

    READ_A(1, 1);
    if (full) STAGEA(0, 1, t2);
    block_barrier(); WAITL(); MFMA_P(1); block_barrier();

    READ_A(1, 2);
    if (full) STAGEB(1, 0, t3);
    block_barrier(); WAITL(); MFMA_P(2); block_barrier();

    READ_A(1, 3);
    if (full) STAGEB(1, 1, t3);
    if (full) asm volatile("s_waitcnt vmcnt(4)" ::: "memory");  // tile t2 landed
    block_barrier(); WAITL(); MFMA_P(3); block_barrier();
  }
#undef STAGEA
#undef STAGEB
#undef READ_A
#undef READ_B
#undef WAITL
#undef MFMA_P

  // epilogue: D layout col=lane&15, row=(lane>>4)*4+reg  [guide-verified]
#pragma unroll
  for (int fm = 0; fm < 8; fm++) {
    long rowb = tileM + wm * 128 + fm * 16 + g * 4;
#pragma unroll
    for (int fn = 0; fn < 4; fn++) {
      long cn = tileN + wn * 64 + fn * 16 + r;
      float bv = bias[cn];
      Cqk[(rowb + 0) * ldc + cn] = f2bf(acc[fm][fn][0] + bv);
      Cqk[(rowb + 1) * ldc + cn] = f2bf(acc[fm][fn][1] + bv);
      Cqk[(rowb + 2) * ldc + cn] = f2bf(acc[fm][fn][2] + bv);
      Cqk[(rowb + 3) * ldc + cn] = f2bf(acc[fm][fn][3] + bv);
    }
  }
}

// ---------------- GEMM (2-phase 128² dbuf) ----------------
// MODE 0: fp32 out with ldc stride (output projection).
// MODE 2: V projection — all cols are V; store to vT2[((b*16+h)*64+dk)*1024 + perm(n)]
//         (head-major, dk row, token permuted: PV-fragment-ready for attention).
template <int MODE>
__global__ __launch_bounds__(256) void gemm_bt(const short* __restrict__ A,
                                               const short* __restrict__ Bt,
                                               const float* __restrict__ bias,
                                               void* __restrict__ Cout,
                                               short* __restrict__ vT,
                                               int M, int N, int K, int ldc) {
  __shared__ __align__(16) short As[2][128 * 32];
  __shared__ __align__(16) short Bs[2][128 * 32];
  const int tid = threadIdx.x;
  const int w = tid >> 6, lane = tid & 63;
  const int r = lane & 15, g = lane >> 4;
  const int wm = w >> 1, wn = w & 1;

  const int nwg = gridDim.x * gridDim.y;
  const int flat = blockIdx.y * gridDim.x + blockIdx.x;
  const int swz = (flat & 7) * (nwg >> 3) + (flat >> 3);
  const int bx = swz % gridDim.x, by = swz / gridDim.x;

  const long tileM = (long)by * 128;
  const long tileN = (long)bx * 128;

  f32x4 acc[4][4] = {};

  const int rowInChunk = lane >> 2;
  const int colOff = ((lane & 3) ^ ((lane >> 3) & 3)) * 8;
  const int rdChunk = (g ^ ((r >> 1) & 3)) * 8;

  const int nt = K >> 5;
#pragma unroll
  for (int issue = 0; issue < 2; ++issue) {
    int c = w * 2 + issue;
    gload_lds16(A + (tileM + c * 16 + rowInChunk) * (long)K + colOff, &As[0][c * 512], lane);
    gload_lds16(Bt + (tileN + c * 16 + rowInChunk) * (long)K + colOff, &Bs[0][c * 512], lane);
  }
  __syncthreads();

  for (int t = 0; t < nt; ++t) {
    const int cur = t & 1;
    if (t + 1 < nt) {
      const int k0 = (t + 1) << 5;
#pragma unroll
      for (int issue = 0; issue < 2; ++issue) {
        int c = w * 2 + issue;
        gload_lds16(A + (tileM + c * 16 + rowInChunk) * (long)K + k0 + colOff,
                    &As[cur ^ 1][c * 512], lane);
        gload_lds16(Bt + (tileN + c * 16 + rowInChunk) * (long)K + k0 + colOff,
                    &Bs[cur ^ 1][c * 512], lane);
      }
    }

    bf16x8 a[4], b[4];
#pragma unroll
    for (int i = 0; i < 4; i++)
      a[i] = *(const bf16x8*)&As[cur][(wm * 64 + i * 16 + r) * 32 + rdChunk];
#pragma unroll
    for (int i = 0; i < 4; i++)
      b[i] = *(const bf16x8*)&Bs[cur][(wn * 64 + i * 16 + r) * 32 + rdChunk];
#pragma unroll
    for (int i = 0; i < 4; i++)
#pragma unroll
      for (int ii = 0; ii < 4; ii++)
        acc[i][ii] = __builtin_amdgcn_mfma_f32_16x16x32_bf16(a[i], b[ii], acc[i][ii], 0, 0, 0);

    __syncthreads();
  }

#pragma unroll
  for (int i = 0; i < 4; i++) {
    long rowb = tileM + wm * 64 + i * 16 + g * 4;
#pragma unroll
    for (int ii = 0; ii < 4; ii++) {
      long cn = tileN + wn * 64 + ii * 16 + r;
      float bv = bias[cn];
      float v0 = acc[i][ii][0] + bv;
      float v1 = acc[i][ii][1] + bv;
      float v2 = acc[i][ii][2] + bv;
      float v3 = acc[i][ii][3] + bv;
      if constexpr (MODE == 0) {
        float* C = (float*)Cout;
        C[(rowb + 0) * ldc + cn] = v0;
        C[(rowb + 1) * ldc + cn] = v1;
        C[(rowb + 2) * ldc + cn] = v2;
        C[(rowb + 3) * ldc + cn] = v3;
      } else {
        // V -> vT2: head-major, dk row, token permuted (fragment-ready)
        int hc = (int)cn;                      // h = hc>>6, dk = hc&63
        int b = (int)(rowb >> 10);
        int n0 = (int)(rowb & 1023);           // n0 % 4 == 0
        int pos = (n0 & ~31) + 8 * ((n0 >> 2) & 3) + 4 * ((n0 >> 4) & 1);
        long va = ((long)(b * 16 + (hc >> 6)) * 64 + (hc & 63)) * 1024 + pos;
        short4v sv;
        sv[0] = f2bf(v0); sv[1] = f2bf(v1); sv[2] = f2bf(v2); sv[3] = f2bf(v3);
        *(short4v*)&vT[va] = sv;
      }
    }
  }
}

// ---------------- flash attention, 4 waves / block, 128 q-rows / block ----------------
// (unchanged from round 6 — single-buffer 2-barrier, perm-vT single-b128 PV fragments,
//  exp2-domain softmax, defer-max, XCD swizzle)
__global__ __launch_bounds__(256) void attn_kernel(const short* __restrict__ qk,
                                                   const short* __restrict__ vT,
                                                   short* __restrict__ attn_out) {
  __shared__ __align__(16) short Ks[64 * 64];
  __shared__ __align__(16) short Vs[64 * 64];

  const int nwg = gridDim.x * gridDim.y;  // 1024, %8==0
  const int flat = blockIdx.y * gridDim.x + blockIdx.x;
  const int swz = (flat & 7) * (nwg >> 3) + (flat >> 3);
  const int bh = swz >> 3;                // (b*16+h)
  const int qt = swz & 7;

  const int bb = bh >> 4, h = bh & 15;
  const int tid = threadIdx.x;
  const int wid = tid >> 6, lane = tid & 63;
  const int r = lane & 15, g = lane >> 4;
  const int qbase = qt * 128 + wid * 32;
  const int RS = 2048;
  const long base = (long)bb * NN * RS;
  const short* Qp = qk + base + h * 64;
  const short* Kp = qk + base + DD + h * 64;
  const short* vTh = vT + (long)bh * 64 * 1024;

  const int srow0 = 8 * wid + (lane >> 3);
  const int sj = (lane & 7) ^ (lane >> 3);   // pre-swizzled source chunk

  bf16x8 qf[2][2];
#pragma unroll
  for (int qg = 0; qg < 2; qg++) {
    const short* qrow = Qp + (long)(qbase + 16 * qg + r) * RS;
    qf[qg][0] = *(const bf16x8*)(qrow + 8 * g);
    qf[qg][1] = *(const bf16x8*)(qrow + 32 + 8 * g);
  }

  const float C = 0.18033688f;     // 0.125 * log2(e)
  float m2[2] = {-3e38f, -3e38f}, lsum[2] = {0.0f, 0.0f};
  f32x4 o[2][4] = {};

  for (int kv0 = 0; kv0 < NN; kv0 += 64) {
    __syncthreads();
#pragma unroll
    for (int i = 0; i < 2; i++) {
      int srow = 32 * i + srow0;
      gload_lds16(Kp + (long)(kv0 + srow) * RS + sj * 8, &Ks[i * 2048 + wid * 512], lane);
      gload_lds16(vTh + (long)srow * 1024 + kv0 + sj * 8, &Vs[i * 2048 + wid * 512], lane);
    }
    __syncthreads();

    bf16x8 kf[2][2][2];
#pragma unroll
    for (int c = 0; c < 2; c++)
#pragma unroll
      for (int u = 0; u < 2; u++) {
        int krow = 32 * c + 16 * u + r;
#pragma unroll
        for (int s = 0; s < 2; s++)
          kf[c][u][s] = *(const bf16x8*)&Ks[krow * 64 + (((4 * s + g) ^ (r & 7)) * 8)];
      }

    bf16x8 pf[2][2];
#pragma unroll
    for (int qg = 0; qg < 2; qg++) {
      f32x4 s[2][2];
      __builtin_amdgcn_s_setprio(1);
#pragma unroll
      for (int c = 0; c < 2; c++)
#pragma unroll
        for (int u = 0; u < 2; u++) {
          f32x4 t = {};
          t = __builtin_amdgcn_mfma_f32_16x16x32_bf16(kf[c][u][0], qf[qg][0], t, 0, 0, 0);
          s[c][u] = __builtin_amdgcn_mfma_f32_16x16x32_bf16(kf[c][u][1], qf[qg][1], t, 0, 0, 0);
        }
      __builtin_amdgcn_s_setprio(0);

      float s16[16];
#pragma unroll
      for (int c = 0; c < 2; c++)
#pragma unroll
        for (int j = 0; j < 4; j++) {
          s16[8 * c + j] = s[c][0][j];
          s16[8 * c + 4 + j] = s[c][1][j];
        }

      float t8[8];
#pragma unroll
      for (int j = 0; j < 8; j++) t8[j] = fmaxf(s16[j], s16[j + 8]);
#pragma unroll
      for (int j = 0; j < 4; j++) t8[j] = fmaxf(t8[j], t8[j + 4]);
      float tmax = fmaxf(fmaxf(t8[0], t8[1]), fmaxf(t8[2], t8[3]));
      tmax = fmaxf(tmax, __shfl_xor(tmax, 16));
      tmax = fmaxf(tmax, __shfl_xor(tmax, 32));
      float tm2 = tmax * C;

      if (!__all(tm2 <= m2[qg] + 11.5416f)) {
        float mnew = fmaxf(m2[qg], tm2);
        float corr = fexp2(m2[qg] - mnew);
#pragma unroll
        for (int t = 0; t < 4; t++)
#pragma unroll
          for (int j = 0; j < 4; j++) o[qg][t][j] *= corr;
        lsum[qg] *= corr;
        m2[qg] = mnew;
      }

      float pv[16];
#pragma unroll
      for (int j = 0; j < 16; j++) pv[j] = fexp2(fmaf(s16[j], C, -m2[qg]));
      float s8[8];
#pragma unroll
      for (int j = 0; j < 8; j++) s8[j] = pv[j] + pv[j + 8];
#pragma unroll
      for (int j = 0; j < 4; j++) s8[j] = s8[j] + s8[j + 4];
      float ps = (s8[0] + s8[1]) + (s8[2] + s8[3]);
      ps += __shfl_xor(ps, 16);
      ps += __shfl_xor(ps, 32);
      lsum[qg] += ps;
#pragma unroll
      for (int c = 0; c < 2; c++)
#pragma unroll
        for (int j = 0; j < 8; j++) pf[qg][c][j] = f2bf_rn(pv[8 * c + j]);
    }

#pragma unroll
    for (int t = 0; t < 4; t++) {
      int vrow = 16 * t + r;
#pragma unroll
      for (int c = 0; c < 2; c++) {
        bf16x8 vt = *(const bf16x8*)&Vs[vrow * 64 + (((4 * c + g) ^ (r & 7)) * 8)];
        __builtin_amdgcn_s_setprio(1);
        o[0][t] = __builtin_amdgcn_mfma_f32_16x16x32_bf16(vt, pf[0][c], o[0][t], 0, 0, 0);
        o[1][t] = __builtin_amdgcn_mfma_f32_16x16x32_bf16(vt, pf[1][c], o[1][t], 0, 0, 0);
        __builtin_amdgcn_s_setprio(0);
      }
    }
  }

#pragma unroll
  for (int qg = 0; qg < 2; qg++) {
    float inv = 1.0f / lsum[qg];
    long orow = (long)(bb * NN + qbase + 16 * qg + r) * DD + h * 64;
#pragma unroll
    for (int t = 0; t < 4; t++) {
      short4v svv;
#pragma unroll
      for (int j = 0; j < 4; j++) svv[j] = f2bf(o[qg][t][j] * inv);
      *(short4v*)&attn_out[orow + 16 * t + 4 * g] = svv;
    }
  }
}

extern "C" void kernel_launch(void* const* d_in, const int* in_sizes, int n_in,
                              void* d_out, int out_size, void* d_ws, size_t ws_size,
                              hipStream_t stream) {
  const float* x = (const float*)d_in[0];
  const float* w_qkv = (const float*)d_in[1];
  const float* b_qkv = (const float*)d_in[2];
  const float* w_proj = (const float*)d_in[3];
  const float* b_proj = (const float*)d_in[4];
  float* out = (float*)d_out;

  short* ws = (short*)d_ws;
  short* xb = ws;                                // 8192*1024
  short* wqkvT = xb + (long)TOK * DD;            // 3072*1024
  short* wprojT = wqkvT + (long)QKVN * DD;       // 1024*1024
  short* qkb = wprojT + (long)DD * DD;           // 8192*2048 (Q,K only)
  short* vT = qkb + (long)TOK * 2048;            // 8192*1024 (V, head-major, perm order)
  short* attn = vT + (long)TOK * DD;             // 8192*1024
  // total 46,137,344 shorts = 88 MiB of workspace

  // 1) casts
  cast_f32_bf16<<<(TOK * DD) / (256 * 4), 256, 0, stream>>>(x, xb, (long)TOK * DD);
  transpose_cast<<<dim3(QKVN / 32, DD / 32), dim3(32, 8), 0, stream>>>(w_qkv, wqkvT, DD, QKVN);
  transpose_cast<<<dim3(DD / 32, DD / 32), dim3(32, 8), 0, stream>>>(w_proj, wprojT, DD, DD);

  // 2a) QK projection (256² 8-phase, exactly 256 blocks = 1 round)
  gemm256<<<dim3(2048 / 256, TOK / 256), 512, 0, stream>>>(xb, wqkvT, b_qkv, qkb,
                                                           TOK, 2048, DD, 2048);

  // 2b) V projection (2-phase 128², multi-block/CU regime) -> vT2 perm layout
  gemm_bt<2><<<dim3(DD / 128, TOK / 128), 256, 0, stream>>>(
      xb, wqkvT + (long)2048 * DD, b_qkv + 2048, nullptr, vT, TOK, DD, DD, 0);

  // 3) attention: 8 q-tiles (128 rows) x 128 (b,h) pairs, 4 waves/block
  attn_kernel<<<dim3(8, BB * HH), 256, 0, stream>>>(qkb, vT, attn);

  // 4) output projection: out = attn @ w_proj + b_proj  (fp32 out)
  gemm_bt<0><<<dim3(DD / 128, TOK / 128), 256, 0, stream>>>(attn, wprojT, b_proj, out, nullptr,
                                                            TOK, DD, DD, DD);
}

// Round 9
// 158.025 us; speedup vs baseline: 2.5664x; 1.1174x over previous
//
#include <hip/hip_runtime.h>
#include <hip/hip_bf16.h>

// Problem: MultiHeadSelfAttention  B=8, N=1024, D=1024, H=16, DK=64
// x:(8,1024,1024) f32, w_qkv:(1024,3072) f32, b_qkv:(3072,), w_proj:(1024,1024), b_proj:(1024,)
// out:(8,1024,1024) f32

#define BB 8
#define NN 1024
#define DD 1024
#define HH 16
#define DK 64
#define TOK (BB * NN)        // 8192 tokens
#define QKVN (3 * DD)        // 3072

typedef __attribute__((ext_vector_type(8))) short bf16x8;
typedef __attribute__((ext_vector_type(4))) float f32x4;
typedef __attribute__((ext_vector_type(4))) short short4v;
typedef __attribute__((ext_vector_type(4))) float float4v;

// manual RNE bf16 cast (cold paths)
static __device__ __forceinline__ short f2bf(float f) {
  union { float f; unsigned u; } v; v.f = f;
  unsigned r = (v.u + 0x7FFFu + ((v.u >> 16) & 1u)) >> 16;
  return (short)r;
}
// HIP cast (hot path: compiler emits v_cvt_pk_bf16_f32 pairs — m240)
static __device__ __forceinline__ short f2bf_rn(float f) {
  __hip_bfloat16 h(f);
  short s;
  __builtin_memcpy(&s, &h, 2);
  return s;
}
// raw hardware exp2 (v_exp_f32 IS 2^x)
static __device__ __forceinline__ float fexp2(float x) {
#if __has_builtin(__builtin_amdgcn_exp2f)
  return __builtin_amdgcn_exp2f(x);
#else
  return __expf(x * 0.69314718056f);
#endif
}

// async global->LDS, 16B per lane. LDS dest = wave-uniform base + lane*16B.
static __device__ __forceinline__ void gload_lds16(const short* g, short* lds, int lane) {
#if __has_builtin(__builtin_amdgcn_global_load_lds)
  __builtin_amdgcn_global_load_lds((const __attribute__((address_space(1))) void*)g,
                                   (__attribute__((address_space(3))) void*)lds, 16, 0, 0);
#else
  ((bf16x8*)lds)[lane] = *(const bf16x8*)g;
#endif
}

// raw barrier WITHOUT the implicit vmcnt(0)/lgkmcnt(0) drain of __syncthreads (T4).
static __device__ __forceinline__ void block_barrier() {
  asm volatile("" ::: "memory");
  __builtin_amdgcn_s_barrier();
  asm volatile("" ::: "memory");
}

// ---------------- cast x (f32 -> bf16), 4 elems/thread ----------------
__global__ __launch_bounds__(256) void cast_f32_bf16(const float* __restrict__ in,
                                                     short* __restrict__ out, long n) {
  long i = ((long)blockIdx.x * blockDim.x + threadIdx.x) * 4;
  if (i >= n) return;
  float4v v = *(const float4v*)(in + i);
  short4v o;
  o[0] = f2bf(v[0]); o[1] = f2bf(v[1]); o[2] = f2bf(v[2]); o[3] = f2bf(v[3]);
  *(short4v*)(out + i) = o;
}

// ------------- transpose-cast: in[rows][cols] f32 -> out[cols][rows] bf16 -------------
__global__ __launch_bounds__(256) void transpose_cast(const float* __restrict__ in,
                                                      short* __restrict__ out,
                                                      int rows, int cols) {
  __shared__ float tile[32][33];
  int bx = blockIdx.x * 32;  // col base
  int by = blockIdx.y * 32;  // row base
  int tx = threadIdx.x, ty = threadIdx.y;  // 32 x 8
#pragma unroll
  for (int q = 0; q < 4; q++)
    tile[ty + 8 * q][tx] = in[(long)(by + ty + 8 * q) * cols + bx + tx];
  __syncthreads();
#pragma unroll
  for (int q = 0; q < 4; q++)
    out[(long)(bx + ty + 8 * q) * rows + by + tx] = f2bf(tile[tx][ty + 8 * q]);
}

// ================= QK projection: 256x256 tile, BK=64, 8-phase counted-vmcnt ==========
// (unchanged from round 7)
__global__ __launch_bounds__(512, 2) void gemm256(const short* __restrict__ A,
                                                  const short* __restrict__ Bt,
                                                  const float* __restrict__ bias,
                                                  short* __restrict__ Cqk,
                                                  int M, int N, int K, int ldc) {
  __shared__ __align__(16) short lds[2][2][2][128 * 64];
  const int tid = threadIdx.x;
  const int wid = tid >> 6, lane = tid & 63;
  const int r = lane & 15, g = lane >> 4;
  const int wm = wid >> 2, wn = wid & 3;

  const int nwg = gridDim.x * gridDim.y;
  const int flat = blockIdx.y * gridDim.x + blockIdx.x;
  const int swz = (flat & 7) * (nwg >> 3) + (flat >> 3);
  const int bx = swz % gridDim.x, by = swz / gridDim.x;
  const long tileM = (long)by * 256, tileN = (long)bx * 256;

  f32x4 acc[8][4] = {};

  const int sc = ((lane & 7) ^ ((lane >> 3) & 7)) * 8;  // pre-swizzled source chunk
  const int srl = lane >> 3;                            // row-in-8-group

  const int akc0 = ((0 + g) ^ (r & 7)) * 8;
  const int akc1 = ((4 + g) ^ (r & 7)) * 8;
  const int bn0 = (wn & 1) * 64;
  const int bhh = wn >> 1;

#define STAGEA(buf, h, Tt)                                                          \
  {                                                                                 \
    _Pragma("unroll") for (int j = 0; j < 2; j++)                                   \
      gload_lds16(A + (tileM + (h) * 128 + wid * 16 + j * 8 + srl) * (long)K +      \
                      (Tt) * 64 + sc,                                               \
                  &lds[buf][0][h][(wid * 2 + j) * 512], lane);                      \
  }
#define STAGEB(buf, h, Tt)                                                          \
  {                                                                                 \
    _Pragma("unroll") for (int j = 0; j < 2; j++)                                   \
      gload_lds16(Bt + (tileN + (h) * 128 + wid * 16 + j * 8 + srl) * (long)K +     \
                      (Tt) * 64 + sc,                                               \
                  &lds[buf][1][h][(wid * 2 + j) * 512], lane);                      \
  }
#define READ_A(q, p)                                                                \
  af[0][0] = *(const bf16x8*)&lds[q][0][wm][((p) * 32 + r) * 64 + akc0];            \
  af[0][1] = *(const bf16x8*)&lds[q][0][wm][((p) * 32 + r) * 64 + akc1];            \
  af[1][0] = *(const bf16x8*)&lds[q][0][wm][((p) * 32 + 16 + r) * 64 + akc0];       \
  af[1][1] = *(const bf16x8*)&lds[q][0][wm][((p) * 32 + 16 + r) * 64 + akc1];
#define READ_B(q)                                                                   \
  {                                                                                 \
    const short* Bh = &lds[q][1][bhh][0];                                           \
    _Pragma("unroll") for (int fn = 0; fn < 4; fn++) {                              \
      bf[fn][0] = *(const bf16x8*)&Bh[(bn0 + fn * 16 + r) * 64 + akc0];             \
      bf[fn][1] = *(const bf16x8*)&Bh[(bn0 + fn * 16 + r) * 64 + akc1];             \
    }                                                                               \
  }
#define WAITL()                                                                     \
  asm volatile("s_waitcnt lgkmcnt(0)" ::: "memory");                                \
  __builtin_amdgcn_sched_barrier(0);
#define MFMA_P(p)                                                                   \
  __builtin_amdgcn_s_setprio(1);                                                    \
  _Pragma("unroll") for (int fmi = 0; fmi < 2; fmi++)                               \
      _Pragma("unroll") for (int fn = 0; fn < 4; fn++) {                            \
    acc[2 * (p) + fmi][fn] = __builtin_amdgcn_mfma_f32_16x16x32_bf16(               \
        af[fmi][0], bf[fn][0], acc[2 * (p) + fmi][fn], 0, 0, 0);                    \
    acc[2 * (p) + fmi][fn] = __builtin_amdgcn_mfma_f32_16x16x32_bf16(               \
        af[fmi][1], bf[fn][1], acc[2 * (p) + fmi][fn], 0, 0, 0);                    \
  }                                                                                 \
  __builtin_amdgcn_s_setprio(0);

  const int NT = K >> 6;    // 16 K-tiles
  const int NIT = NT >> 1;  // 8 iterations (2 K-tiles each)

  STAGEA(0, 0, 0); STAGEA(0, 1, 0); STAGEB(0, 0, 0); STAGEB(0, 1, 0);
  STAGEB(1, 0, 1); STAGEB(1, 1, 1);
  asm volatile("s_waitcnt vmcnt(4)" ::: "memory");
  block_barrier();

  for (int i = 0; i < NIT; ++i) {
    const int t1 = 2 * i + 1, t2 = 2 * i + 2, t3 = 2 * i + 3;
    const bool full = (i < NIT - 1);
    bf16x8 af[2][2], bf[4][2];

    READ_A(0, 0); READ_B(0);
    STAGEA(1, 0, t1);
    block_barrier(); WAITL(); MFMA_P(0); block_barrier();

    READ_A(0, 1);
    STAGEA(1, 1, t1);
    block_barrier(); WAITL(); MFMA_P(1); block_barrier();

    READ_A(0, 2);
    if (full) STAGEB(0, 0, t2);
    block_barrier(); WAITL(); MFMA_P(2); block_barrier();

    READ_A(0, 3);
    if (full) STAGEB(0, 1, t2);
    if (full) asm volatile("s_waitcnt vmcnt(4)" ::: "memory");
    else      asm volatile("s_waitcnt vmcnt(0)" ::: "memory");
    block_barrier(); WAITL(); MFMA_P(3); block_barrier();

    READ_A(1, 0); READ_B(1);
    if (full) STAGEA(0, 0, t2);
    block_barrier(); WAITL(); MFMA_P(0); block_barrier();

    READ_A(1, 1);
    if (full) STAGEA(0, 1, t2);
    block_barrier(); WAITL(); MFMA_P(1); block_barrier();

    READ_A(1, 2);
    if (full) STAGEB(1, 0, t3);
    block_barrier(); WAITL(); MFMA_P(2); block_barrier();

    READ_A(1, 3);
    if (full) STAGEB(1, 1, t3);
    if (full) asm volatile("s_waitcnt vmcnt(4)" ::: "memory");
    block_barrier(); WAITL(); MFMA_P(3); block_barrier();
  }
#undef STAGEA
#undef STAGEB
#undef READ_A
#undef READ_B
#undef WAITL
#undef MFMA_P

#pragma unroll
  for (int fm = 0; fm < 8; fm++) {
    long rowb = tileM + wm * 128 + fm * 16 + g * 4;
#pragma unroll
    for (int fn = 0; fn < 4; fn++) {
      long cn = tileN + wn * 64 + fn * 16 + r;
      float bv = bias[cn];
      Cqk[(rowb + 0) * ldc + cn] = f2bf(acc[fm][fn][0] + bv);
      Cqk[(rowb + 1) * ldc + cn] = f2bf(acc[fm][fn][1] + bv);
      Cqk[(rowb + 2) * ldc + cn] = f2bf(acc[fm][fn][2] + bv);
      Cqk[(rowb + 3) * ldc + cn] = f2bf(acc[fm][fn][3] + bv);
    }
  }
}

// ---------------- GEMM (2-phase 128² dbuf) ----------------
// MODE 0: fp32 out with ldc stride (output projection).
// MODE 2: V projection — store to vT2[((b*16+h)*64+dk)*1024 + perm(n)].
template <int MODE>
__global__ __launch_bounds__(256) void gemm_bt(const short* __restrict__ A,
                                               const short* __restrict__ Bt,
                                               const float* __restrict__ bias,
                                               void* __restrict__ Cout,
                                               short* __restrict__ vT,
                                               int M, int N, int K, int ldc) {
  __shared__ __align__(16) short As[2][128 * 32];
  __shared__ __align__(16) short Bs[2][128 * 32];
  const int tid = threadIdx.x;
  const int w = tid >> 6, lane = tid & 63;
  const int r = lane & 15, g = lane >> 4;
  const int wm = w >> 1, wn = w & 1;

  const int nwg = gridDim.x * gridDim.y;
  const int flat = blockIdx.y * gridDim.x + blockIdx.x;
  const int swz = (flat & 7) * (nwg >> 3) + (flat >> 3);
  const int bx = swz % gridDim.x, by = swz / gridDim.x;

  const long tileM = (long)by * 128;
  const long tileN = (long)bx * 128;

  f32x4 acc[4][4] = {};

  const int rowInChunk = lane >> 2;
  const int colOff = ((lane & 3) ^ ((lane >> 3) & 3)) * 8;
  const int rdChunk = (g ^ ((r >> 1) & 3)) * 8;

  const int nt = K >> 5;
#pragma unroll
  for (int issue = 0; issue < 2; ++issue) {
    int c = w * 2 + issue;
    gload_lds16(A + (tileM + c * 16 + rowInChunk) * (long)K + colOff, &As[0][c * 512], lane);
    gload_lds16(Bt + (tileN + c * 16 + rowInChunk) * (long)K + colOff, &Bs[0][c * 512], lane);
  }
  __syncthreads();

  for (int t = 0; t < nt; ++t) {
    const int cur = t & 1;
    if (t + 1 < nt) {
      const int k0 = (t + 1) << 5;
#pragma unroll
      for (int issue = 0; issue < 2; ++issue) {
        int c = w * 2 + issue;
        gload_lds16(A + (tileM + c * 16 + rowInChunk) * (long)K + k0 + colOff,
                    &As[cur ^ 1][c * 512], lane);
        gload_lds16(Bt + (tileN + c * 16 + rowInChunk) * (long)K + k0 + colOff,
                    &Bs[cur ^ 1][c * 512], lane);
      }
    }

    bf16x8 a[4], b[4];
#pragma unroll
    for (int i = 0; i < 4; i++)
      a[i] = *(const bf16x8*)&As[cur][(wm * 64 + i * 16 + r) * 32 + rdChunk];
#pragma unroll
    for (int i = 0; i < 4; i++)
      b[i] = *(const bf16x8*)&Bs[cur][(wn * 64 + i * 16 + r) * 32 + rdChunk];
#pragma unroll
    for (int i = 0; i < 4; i++)
#pragma unroll
      for (int ii = 0; ii < 4; ii++)
        acc[i][ii] = __builtin_amdgcn_mfma_f32_16x16x32_bf16(a[i], b[ii], acc[i][ii], 0, 0, 0);

    __syncthreads();
  }

#pragma unroll
  for (int i = 0; i < 4; i++) {
    long rowb = tileM + wm * 64 + i * 16 + g * 4;
#pragma unroll
    for (int ii = 0; ii < 4; ii++) {
      long cn = tileN + wn * 64 + ii * 16 + r;
      float bv = bias[cn];
      float v0 = acc[i][ii][0] + bv;
      float v1 = acc[i][ii][1] + bv;
      float v2 = acc[i][ii][2] + bv;
      float v3 = acc[i][ii][3] + bv;
      if constexpr (MODE == 0) {
        float* C = (float*)Cout;
        C[(rowb + 0) * ldc + cn] = v0;
        C[(rowb + 1) * ldc + cn] = v1;
        C[(rowb + 2) * ldc + cn] = v2;
        C[(rowb + 3) * ldc + cn] = v3;
      } else {
        // V -> vT2: head-major, dk row, token permuted (fragment-ready)
        int hc = (int)cn;                      // h = hc>>6, dk = hc&63
        int b = (int)(rowb >> 10);
        int n0 = (int)(rowb & 1023);           // n0 % 4 == 0
        int pos = (n0 & ~31) + 8 * ((n0 >> 2) & 3) + 4 * ((n0 >> 4) & 1);
        long va = ((long)(b * 16 + (hc >> 6)) * 64 + (hc & 63)) * 1024 + pos;
        short4v sv;
        sv[0] = f2bf(v0); sv[1] = f2bf(v1); sv[2] = f2bf(v2); sv[3] = f2bf(v3);
        *(short4v*)&vT[va] = sv;
      }
    }
  }
}

// ---------------- flash attention, 8 waves / block, 256 q-rows / block ----------------
// One staged K/V tile (64 kv, 16 KB LDS) now feeds 8 waves (256 q-rows): staging
// instructions and barrier count per unit compute are HALVED vs the 4-wave version.
// Single-buffer, 2 barriers/iter. qk[(b*N+n)][2048]; vT2 perm layout; swapped QK^T;
// exp2-domain softmax with defer-max; XCD swizzle.
__global__ __launch_bounds__(512) void attn_kernel(const short* __restrict__ qk,
                                                   const short* __restrict__ vT,
                                                   short* __restrict__ attn_out) {
  __shared__ __align__(16) short Ks[64 * 64];
  __shared__ __align__(16) short Vs[64 * 64];

  const int nwg = gridDim.x * gridDim.y;  // 512, %8==0
  const int flat = blockIdx.y * gridDim.x + blockIdx.x;
  const int swz = (flat & 7) * (nwg >> 3) + (flat >> 3);
  const int bh = swz >> 2;                // (b*16+h)
  const int qt = swz & 3;

  const int bb = bh >> 4, h = bh & 15;
  const int tid = threadIdx.x;
  const int wid = tid >> 6, lane = tid & 63;  // wid 0..7
  const int r = lane & 15, g = lane >> 4;
  const int qbase = qt * 256 + wid * 32;
  const int RS = 2048;
  const long base = (long)bb * NN * RS;
  const short* Qp = qk + base + h * 64;
  const short* Kp = qk + base + DD + h * 64;
  const short* vTh = vT + (long)bh * 64 * 1024;

  // staging: wave wid covers rows 8*wid..8*wid+7 (one gload each for K and V)
  const int srow = 8 * wid + (lane >> 3);
  const int sj = (lane & 7) ^ (lane >> 3);   // pre-swizzled source chunk

  bf16x8 qf[2][2];
#pragma unroll
  for (int qg = 0; qg < 2; qg++) {
    const short* qrow = Qp + (long)(qbase + 16 * qg + r) * RS;
    qf[qg][0] = *(const bf16x8*)(qrow + 8 * g);
    qf[qg][1] = *(const bf16x8*)(qrow + 32 + 8 * g);
  }

  const float C = 0.18033688f;     // 0.125 * log2(e)
  float m2[2] = {-3e38f, -3e38f}, lsum[2] = {0.0f, 0.0f};
  f32x4 o[2][4] = {};

  for (int kv0 = 0; kv0 < NN; kv0 += 64) {
    __syncthreads();
    gload_lds16(Kp + (long)(kv0 + srow) * RS + sj * 8, &Ks[wid * 512], lane);
    gload_lds16(vTh + (long)srow * 1024 + kv0 + sj * 8, &Vs[wid * 512], lane);
    __syncthreads();

    bf16x8 kf[2][2][2];
#pragma unroll
    for (int c = 0; c < 2; c++)
#pragma unroll
      for (int u = 0; u < 2; u++) {
        int krow = 32 * c + 16 * u + r;
#pragma unroll
        for (int s = 0; s < 2; s++)
          kf[c][u][s] = *(const bf16x8*)&Ks[krow * 64 + (((4 * s + g) ^ (r & 7)) * 8)];
      }

    bf16x8 pf[2][2];
#pragma unroll
    for (int qg = 0; qg < 2; qg++) {
      f32x4 s[2][2];
      __builtin_amdgcn_s_setprio(1);
#pragma unroll
      for (int c = 0; c < 2; c++)
#pragma unroll
        for (int u = 0; u < 2; u++) {
          f32x4 t = {};
          t = __builtin_amdgcn_mfma_f32_16x16x32_bf16(kf[c][u][0], qf[qg][0], t, 0, 0, 0);
          s[c][u] = __builtin_amdgcn_mfma_f32_16x16x32_bf16(kf[c][u][1], qf[qg][1], t, 0, 0, 0);
        }
      __builtin_amdgcn_s_setprio(0);

      float s16[16];
#pragma unroll
      for (int c = 0; c < 2; c++)
#pragma unroll
        for (int j = 0; j < 4; j++) {
          s16[8 * c + j] = s[c][0][j];
          s16[8 * c + 4 + j] = s[c][1][j];
        }

      float t8[8];
#pragma unroll
      for (int j = 0; j < 8; j++) t8[j] = fmaxf(s16[j], s16[j + 8]);
#pragma unroll
      for (int j = 0; j < 4; j++) t8[j] = fmaxf(t8[j], t8[j + 4]);
      float tmax = fmaxf(fmaxf(t8[0], t8[1]), fmaxf(t8[2], t8[3]));
      tmax = fmaxf(tmax, __shfl_xor(tmax, 16));
      tmax = fmaxf(tmax, __shfl_xor(tmax, 32));
      float tm2 = tmax * C;

      if (!__all(tm2 <= m2[qg] + 11.5416f)) {
        float mnew = fmaxf(m2[qg], tm2);
        float corr = fexp2(m2[qg] - mnew);
#pragma unroll
        for (int t = 0; t < 4; t++)
#pragma unroll
          for (int j = 0; j < 4; j++) o[qg][t][j] *= corr;
        lsum[qg] *= corr;
        m2[qg] = mnew;
      }

      float pv[16];
#pragma unroll
      for (int j = 0; j < 16; j++) pv[j] = fexp2(fmaf(s16[j], C, -m2[qg]));
      float s8[8];
#pragma unroll
      for (int j = 0; j < 8; j++) s8[j] = pv[j] + pv[j + 8];
#pragma unroll
      for (int j = 0; j < 4; j++) s8[j] = s8[j] + s8[j + 4];
      float ps = (s8[0] + s8[1]) + (s8[2] + s8[3]);
      ps += __shfl_xor(ps, 16);
      ps += __shfl_xor(ps, 32);
      lsum[qg] += ps;
#pragma unroll
      for (int c = 0; c < 2; c++)
#pragma unroll
        for (int j = 0; j < 8; j++) pf[qg][c][j] = f2bf_rn(pv[8 * c + j]);
    }

#pragma unroll
    for (int t = 0; t < 4; t++) {
      int vrow = 16 * t + r;
#pragma unroll
      for (int c = 0; c < 2; c++) {
        bf16x8 vt = *(const bf16x8*)&Vs[vrow * 64 + (((4 * c + g) ^ (r & 7)) * 8)];
        __builtin_amdgcn_s_setprio(1);
        o[0][t] = __builtin_amdgcn_mfma_f32_16x16x32_bf16(vt, pf[0][c], o[0][t], 0, 0, 0);
        o[1][t] = __builtin_amdgcn_mfma_f32_16x16x32_bf16(vt, pf[1][c], o[1][t], 0, 0, 0);
        __builtin_amdgcn_s_setprio(0);
      }
    }
  }

#pragma unroll
  for (int qg = 0; qg < 2; qg++) {
    float inv = 1.0f / lsum[qg];
    long orow = (long)(bb * NN + qbase + 16 * qg + r) * DD + h * 64;
#pragma unroll
    for (int t = 0; t < 4; t++) {
      short4v svv;
#pragma unroll
      for (int j = 0; j < 4; j++) svv[j] = f2bf(o[qg][t][j] * inv);
      *(short4v*)&attn_out[orow + 16 * t + 4 * g] = svv;
    }
  }
}

extern "C" void kernel_launch(void* const* d_in, const int* in_sizes, int n_in,
                              void* d_out, int out_size, void* d_ws, size_t ws_size,
                              hipStream_t stream) {
  const float* x = (const float*)d_in[0];
  const float* w_qkv = (const float*)d_in[1];
  const float* b_qkv = (const float*)d_in[2];
  const float* w_proj = (const float*)d_in[3];
  const float* b_proj = (const float*)d_in[4];
  float* out = (float*)d_out;

  short* ws = (short*)d_ws;
  short* xb = ws;                                // 8192*1024
  short* wqkvT = xb + (long)TOK * DD;            // 3072*1024
  short* wprojT = wqkvT + (long)QKVN * DD;       // 1024*1024
  short* qkb = wprojT + (long)DD * DD;           // 8192*2048 (Q,K only)
  short* vT = qkb + (long)TOK * 2048;            // 8192*1024 (V, head-major, perm order)
  short* attn = vT + (long)TOK * DD;             // 8192*1024
  // total 46,137,344 shorts = 88 MiB of workspace

  // 1) casts
  cast_f32_bf16<<<(TOK * DD) / (256 * 4), 256, 0, stream>>>(x, xb, (long)TOK * DD);
  transpose_cast<<<dim3(QKVN / 32, DD / 32), dim3(32, 8), 0, stream>>>(w_qkv, wqkvT, DD, QKVN);
  transpose_cast<<<dim3(DD / 32, DD / 32), dim3(32, 8), 0, stream>>>(w_proj, wprojT, DD, DD);

  // 2a) QK projection (256² 8-phase, exactly 256 blocks = 1 round)
  gemm256<<<dim3(2048 / 256, TOK / 256), 512, 0, stream>>>(xb, wqkvT, b_qkv, qkb,
                                                           TOK, 2048, DD, 2048);

  // 2b) V projection (2-phase 128²) -> vT2 perm layout
  gemm_bt<2><<<dim3(DD / 128, TOK / 128), 256, 0, stream>>>(
      xb, wqkvT + (long)2048 * DD, b_qkv + 2048, nullptr, vT, TOK, DD, DD, 0);

  // 3) attention: 4 q-tiles (256 rows) x 128 (b,h) pairs, 8 waves/block
  attn_kernel<<<dim3(4, BB * HH), 512, 0, stream>>>(qkb, vT, attn);

  // 4) output projection: out = attn @ w_proj + b_proj  (fp32 out)
  gemm_bt<0><<<dim3(DD / 128, TOK / 128), 256, 0, stream>>>(attn, wprojT, b_proj, out, nullptr,
                                                            TOK, DD, DD, DD);
}